// Round 23
// baseline (968.628 us; speedup 1.0000x reference)
//
#include <hip/hip_runtime.h>
#include <math.h>

#define N_TOK 65536
#define HID   256
#define FFDIM 1024
#define QKVM  768
#define EPS_LN 1e-5f

typedef __bf16 bf16x8 __attribute__((ext_vector_type(8)));
typedef __bf16 bf16x4 __attribute__((ext_vector_type(4)));
typedef float  f32x4  __attribute__((ext_vector_type(4)));
typedef unsigned short u16x8 __attribute__((ext_vector_type(8)));

// tanh-form GELU: x * sigmoid(1.59577*x*(1+0.044715*x^2)); |err| <= ~2e-3
__device__ __forceinline__ float gelu_f(float x) {
    const float t = 1.59576912f * x * fmaf(0.044715f, x * x, 1.0f);
    return x / (1.0f + __expf(-t));
}
__device__ __forceinline__ float bf2f(unsigned short u) {
    return __uint_as_float(((unsigned int)u) << 16);
}
__device__ __forceinline__ unsigned short f2bf(float f) {
    unsigned int x = __float_as_uint(f);
    unsigned int r = ((x >> 16) & 1u) + 0x7fffu;
    return (unsigned short)((x + r) >> 16);
}
__device__ __forceinline__ void gload16(const void* g, void* l) {
    __builtin_amdgcn_global_load_lds(
        (const __attribute__((address_space(1))) void*)g,
        (__attribute__((address_space(3))) void*)l, 16, 0, 0);
}

// -- weight fp32 [L,K,M] -> bf16 transposed [L][moff + m*mstride][K], g-scaled
__global__ __launch_bounds__(256) void wconv(
    const float* __restrict__ src, const float* __restrict__ g,
    unsigned short* __restrict__ dst,
    const int K, const int M, const size_t dstLS, const int moff, const int mstride)
{
    const int l = blockIdx.z;
    __shared__ float t[32][33];
    const int r  = threadIdx.x >> 3;
    const int c0 = (threadIdx.x & 7) * 4;
    const int bk = blockIdx.x * 32;
    const int bm = blockIdx.y * 32;
    float4 v4 = *(const float4*)(src + (size_t)l * K * M + (size_t)(bk + r) * M + bm + c0);
    if (g) {
        const float gv = g[(size_t)l * K + bk + r];
        v4.x *= gv; v4.y *= gv; v4.z *= gv; v4.w *= gv;
    }
    t[r][c0] = v4.x; t[r][c0+1] = v4.y; t[r][c0+2] = v4.z; t[r][c0+3] = v4.w;
    __syncthreads();
    ushort4 o;
    o.x = f2bf(t[c0+0][r]);
    o.y = f2bf(t[c0+1][r]);
    o.z = f2bf(t[c0+2][r]);
    o.w = f2bf(t[c0+3][r]);
    *(ushort4*)(dst + (size_t)l * dstLS +
                (size_t)(moff + (bm + r) * mstride) * K + bk + c0) = o;
}

__global__ __launch_bounds__(256) void biasfold(
    const float* __restrict__ W, const float* __restrict__ bias,
    const float* __restrict__ bvec, float* __restrict__ outb,
    const int K, const int M, const size_t outLS, const int moff, const int mstride)
{
    const int l = blockIdx.y;
    const int m = blockIdx.x * 256 + threadIdx.x;
    float acc = bias[(size_t)l * M + m];
    const float* Wl = W + (size_t)l * K * M;
    const float* bv = bvec + (size_t)l * K;
    for (int k = 0; k < K; ++k) acc = fmaf(bv[k], Wl[(size_t)k * M + m], acc);
    outb[(size_t)l * outLS + moff + m * mstride] = acc;
}

__global__ __launch_bounds__(256) void colsum(
    const unsigned short* __restrict__ wt, float* __restrict__ S, const int M)
{
    const int l = blockIdx.y;
    const int j = blockIdx.x * 256 + threadIdx.x;
    const unsigned short* rowp = wt + (size_t)l * M * HID + (size_t)j * HID;
    float s = 0.f;
    for (int k = 0; k < HID; k += 8) {
        const u16x8 u = *(const u16x8*)(rowp + k);
        #pragma unroll
        for (int t = 0; t < 8; ++t) s += bf2f(u[t]);
    }
    S[(size_t)l * M + j] = s;
}

// ------- fp32 -> bf16 cast + fused row stats ---------------------------------
__global__ __launch_bounds__(256) void cast_stats(
    const float* __restrict__ x, unsigned short* __restrict__ hb,
    float* __restrict__ mean, float* __restrict__ rstd)
{
    const int row  = blockIdx.x * 4 + (threadIdx.x >> 6);
    const int lane = threadIdx.x & 63;
    const size_t base = (size_t)row * HID + lane * 4;
    const float4 xv = *(const float4*)(x + base);
    ushort4 o;
    o.x = f2bf(xv.x); o.y = f2bf(xv.y); o.z = f2bf(xv.z); o.w = f2bf(xv.w);
    *(ushort4*)(hb + base) = o;
    float s  = xv.x + xv.y + xv.z + xv.w;
    float s2 = fmaf(xv.x, xv.x, fmaf(xv.y, xv.y, fmaf(xv.z, xv.z, xv.w * xv.w)));
    #pragma unroll
    for (int off = 32; off > 0; off >>= 1) {
        s  += __shfl_xor(s, off, 64);
        s2 += __shfl_xor(s2, off, 64);
    }
    if (lane == 0) {
        const float m   = s * (1.0f / HID);
        const float var = fmaxf(s2 * (1.0f / HID) - m * m, 0.f);
        mean[row] = m;
        rstd[row] = rsqrtf(var + EPS_LN);
    }
}

// ------- 256x256-tile 2-phase GEMM (FFN1/FFN2): gload_lds, 1 barrier/K-tile ---
// 512 threads = 8 waves (2M x 4N); per-wave output 128x64; BK=64; LDS 128 KB
// double-buffered (linear layout). STAGE(next) issued BEFORE compute so the
// compiler's vmcnt(0)-drain at the single __syncthreads lands after ~64 MFMA
// of cover (T3-min schedule). Swapped-MFMA C^T epilogue, LN-fold/GELU (FFN1),
// res + fused next-LN row-stats / f32-out (FFN2, full-row).
template<int K, bool LNEP, bool GELU_EP, bool RES, bool STATS, bool OUTF32>
__global__ __launch_bounds__(512, 1) void gemm_2p(
    const unsigned short* __restrict__ A, const int lda,
    const unsigned short* __restrict__ Wt,
    const float* __restrict__ Bias, const float* __restrict__ S,
    const float* __restrict__ mean, const float* __restrict__ rstd,
    const unsigned short* __restrict__ res,
    void* __restrict__ C, const int ldc, const int nCT,
    float* __restrict__ meanO, float* __restrict__ rstdO)
{
    constexpr int KT = K / 64;
    __shared__ __align__(16) unsigned short Ab[2][256 * 64];   // 64 KB
    __shared__ __align__(16) unsigned short Bb[2][256 * 64];   // 64 KB
    __shared__ float sredS[256][4];
    __shared__ float sredQ[256][4];
    const int tid = threadIdx.x;
    // group/XCD swizzle: groups of 8 row-tiles x nCT col-tiles, row-fastest
    const int gsz = nCT << 3;
    const int grp = blockIdx.x / gsz;
    const int rem = blockIdx.x - grp * gsz;
    const int bm  = ((grp << 3) + (rem & 7)) << 8;   // 256-row tile
    const int bn  = (rem >> 3) << 8;                 // 256-col tile
    // staging: lane covers row tid>>3 (+i*64), 16B chunk tid&7
    const unsigned short* As = A  + (size_t)(bm + (tid >> 3)) * lda + ((tid & 7) << 3);
    const unsigned short* Bs = Wt + (size_t)(bn + (tid >> 3)) * K   + ((tid & 7) << 3);
    const int lane = tid & 63;
    const int wid  = tid >> 6;
    const int wrow = (wid >> 2) << 7;   // 0 / 128
    const int wcol = (wid & 3) << 6;    // 0,64,128,192
    const int lrow = lane & 15;
    const int kgrp = lane >> 4;

    f32x4 acc[8][4];
    #pragma unroll
    for (int i = 0; i < 8; ++i)
        #pragma unroll
        for (int j = 0; j < 4; ++j)
            acc[i][j] = (f32x4){0.f, 0.f, 0.f, 0.f};

    auto STAGE = [&](int buf, int kt) {
        const size_t ko = (size_t)kt * 64;
        unsigned short* ad = &Ab[buf][wid << 9];   // wave-uniform base
        unsigned short* bd = &Bb[buf][wid << 9];
        #pragma unroll
        for (int i = 0; i < 4; ++i) {
            gload16(As + (size_t)(i * 64) * lda + ko, ad + i * 4096);
            gload16(Bs + (size_t)(i * 64) * K   + ko, bd + i * 4096);
        }
    };

    STAGE(0, 0);
    __syncthreads();
    for (int kt = 0; kt < KT; ++kt) {
        const int cur = kt & 1;
        if (kt + 1 < KT) STAGE(cur ^ 1, kt + 1);   // issue BEFORE compute
        #pragma unroll
        for (int ks = 0; ks < 2; ++ks) {
            bf16x8 af[8], bfr[4];
            #pragma unroll
            for (int ni = 0; ni < 4; ++ni)
                bfr[ni] = *(const bf16x8*)&Bb[cur][(wcol + ni * 16 + lrow) * 64 + ks * 32 + kgrp * 8];
            #pragma unroll
            for (int mi = 0; mi < 8; ++mi)
                af[mi] = *(const bf16x8*)&Ab[cur][(wrow + mi * 16 + lrow) * 64 + ks * 32 + kgrp * 8];
            #pragma unroll
            for (int mi = 0; mi < 8; ++mi)
                #pragma unroll
                for (int ni = 0; ni < 4; ++ni)
                    acc[mi][ni] = __builtin_amdgcn_mfma_f32_16x16x32_bf16(
                        bfr[ni], af[mi], acc[mi][ni], 0, 0, 0);   // C^T frags
        }
        __syncthreads();   // drains vmcnt(0): next buf ready; readers done
    }
    // epilogue (C^T frags): row = bm+wrow+mi*16+lrow, cols = bn+wcol+ni*16+kgrp*4..+3
    float4 bcol[4], scol[4];
    #pragma unroll
    for (int ni = 0; ni < 4; ++ni) {
        const int col0 = bn + wcol + ni * 16 + (kgrp << 2);
        bcol[ni] = *(const float4*)(Bias + col0);
        if (LNEP) scol[ni] = *(const float4*)(S + col0);
    }
    float sS[8], sQ[8];
    #pragma unroll
    for (int mi = 0; mi < 8; ++mi) { sS[mi] = 0.f; sQ[mi] = 0.f; }
    #pragma unroll
    for (int mi = 0; mi < 8; ++mi) {
        const int row = bm + wrow + mi * 16 + lrow;
        float mrow = 0.f, rsrow = 0.f;
        if (LNEP) { mrow = mean[row]; rsrow = rstd[row]; }
        const size_t rowC = (size_t)row * ldc;
        const size_t rowR = RES ? (size_t)row * HID : 0;
        #pragma unroll
        for (int ni = 0; ni < 4; ++ni) {
            const int col0 = bn + wcol + ni * 16 + (kgrp << 2);
            float v[4];
            #pragma unroll
            for (int r = 0; r < 4; ++r) v[r] = acc[mi][ni][r];
            if (LNEP) {
                v[0] = fmaf(v[0] - mrow * scol[ni].x, rsrow, bcol[ni].x);
                v[1] = fmaf(v[1] - mrow * scol[ni].y, rsrow, bcol[ni].y);
                v[2] = fmaf(v[2] - mrow * scol[ni].z, rsrow, bcol[ni].z);
                v[3] = fmaf(v[3] - mrow * scol[ni].w, rsrow, bcol[ni].w);
            } else {
                v[0] += bcol[ni].x; v[1] += bcol[ni].y;
                v[2] += bcol[ni].z; v[3] += bcol[ni].w;
            }
            if (RES) {
                const ushort4 rv = *(const ushort4*)(res + rowR + col0);
                v[0] += bf2f(rv.x); v[1] += bf2f(rv.y);
                v[2] += bf2f(rv.z); v[3] += bf2f(rv.w);
            }
            if (GELU_EP) {
                v[0] = gelu_f(v[0]); v[1] = gelu_f(v[1]);
                v[2] = gelu_f(v[2]); v[3] = gelu_f(v[3]);
            }
            if (STATS) {
                sS[mi] += v[0] + v[1] + v[2] + v[3];
                sQ[mi] = fmaf(v[0], v[0], fmaf(v[1], v[1],
                          fmaf(v[2], v[2], fmaf(v[3], v[3], sQ[mi]))));
            }
            if (OUTF32) {
                float4 o = {v[0], v[1], v[2], v[3]};
                *(float4*)((float*)C + rowC + col0) = o;
            } else {
                bf16x4 o = {(__bf16)v[0], (__bf16)v[1], (__bf16)v[2], (__bf16)v[3]};
                *(bf16x4*)((unsigned short*)C + rowC + col0) = o;
            }
        }
    }
    if (STATS) {
        // reduce over the 4 kgrp lanes, then across the 4 N-waves via LDS
        #pragma unroll
        for (int mi = 0; mi < 8; ++mi) {
            sS[mi] += __shfl_xor(sS[mi], 16, 64);
            sS[mi] += __shfl_xor(sS[mi], 32, 64);
            sQ[mi] += __shfl_xor(sQ[mi], 16, 64);
            sQ[mi] += __shfl_xor(sQ[mi], 32, 64);
        }
        if (lane < 16) {
            #pragma unroll
            for (int mi = 0; mi < 8; ++mi) {
                const int ridx = wrow + mi * 16 + lrow;
                sredS[ridx][wid & 3] = sS[mi];
                sredQ[ridx][wid & 3] = sQ[mi];
            }
        }
        __syncthreads();
        if (tid < 256) {
            const float Ssum = sredS[tid][0] + sredS[tid][1] + sredS[tid][2] + sredS[tid][3];
            const float Qsum = sredQ[tid][0] + sredQ[tid][1] + sredQ[tid][2] + sredQ[tid][3];
            const float m    = Ssum * (1.0f / HID);
            const float var  = fmaxf(Qsum * (1.0f / HID) - m * m, 0.f);
            meanO[bm + tid] = m;
            rstdO[bm + tid] = rsqrtf(var + EPS_LN);
        }
    }
}

// ------- 256x128-tile GEMM + 2-deep reg prefetch: QKV (LN-ep + fused reduce) --
template<int K, bool LNEP, bool GELU_EP, bool REDUCE, bool OUTF32>
__global__ __launch_bounds__(256, 2) void gemm_rs(
    const unsigned short* __restrict__ A, const int lda,
    const unsigned short* __restrict__ Wt,
    const float* __restrict__ Bias, const float* __restrict__ S,
    const float* __restrict__ mean, const float* __restrict__ rstd,
    void* __restrict__ C, const int ldc, const int nCT,
    unsigned short* __restrict__ Cv,
    float* __restrict__ pkv, float* __restrict__ pks,
    float* __restrict__ psq, float* __restrict__ psk)
{
    constexpr int KT  = K / 32;          // 8 (even)
    constexpr int LDT = 40;
    __shared__ __align__(16) unsigned short Abuf[2][256 * LDT];   // 40 KB
    __shared__ __align__(16) unsigned short Bbuf[2][128 * LDT];   // 20 KB
    __shared__ float redKV[2][64];
    __shared__ float redKS[2][64];
    __shared__ float sredS[4];
    const int tid = threadIdx.x;
    const int gsz = nCT << 3;
    const int grp = blockIdx.x / gsz;
    const int rem = blockIdx.x - grp * gsz;
    const int bm  = ((grp << 3) + (rem & 7)) << 8;   // 256-row tile (fastest)
    const int bn  = (rem >> 3) << 7;                 // 128-col tile
    const int lr = tid >> 2;
    const int lk = (tid & 3) << 3;
    const unsigned short* Ag = A  + (size_t)(bm + lr) * lda + lk;
    const unsigned short* Bg = Wt + (size_t)(bn + lr) * K   + lk;
    const int lds_off = lr * LDT + lk;

    const int lane = tid & 63;
    const int wv   = tid >> 6;
    const int wr   = (wv >> 1) << 7;   // 0 / 128
    const int wc   = (wv & 1) << 6;    // 0 / 64
    const int lrow = lane & 15;
    const int kgrp = lane >> 4;

    f32x4 acc[8][4];
    #pragma unroll
    for (int i = 0; i < 8; ++i)
        #pragma unroll
        for (int j = 0; j < 4; ++j)
            acc[i][j] = (f32x4){0.f, 0.f, 0.f, 0.f};

    u16x8 aA0, aA1, aA2, aA3, bA0, bA1;
    u16x8 aB0, aB1, aB2, aB3, bB0, bB1;
    #define GLOADA_RS(kt) { const unsigned short* a_ = Ag + (kt) * 32;           \
        const unsigned short* b_ = Bg + (kt) * 32;                               \
        aA0 = *(const u16x8*)a_;                                                 \
        aA1 = *(const u16x8*)(a_ + (size_t)64  * lda);                           \
        aA2 = *(const u16x8*)(a_ + (size_t)128 * lda);                           \
        aA3 = *(const u16x8*)(a_ + (size_t)192 * lda);                           \
        bA0 = *(const u16x8*)b_;                                                 \
        bA1 = *(const u16x8*)(b_ + (size_t)64 * K); }
    #define GLOADB_RS(kt) { const unsigned short* a_ = Ag + (kt) * 32;           \
        const unsigned short* b_ = Bg + (kt) * 32;                               \
        aB0 = *(const u16x8*)a_;                                                 \
        aB1 = *(const u16x8*)(a_ + (size_t)64  * lda);                           \
        aB2 = *(const u16x8*)(a_ + (size_t)128 * lda);                           \
        aB3 = *(const u16x8*)(a_ + (size_t)192 * lda);                           \
        bB0 = *(const u16x8*)b_;                                                 \
        bB1 = *(const u16x8*)(b_ + (size_t)64 * K); }
    #define LSTOREA_RS(buf) {                                                    \
        *(u16x8*)&Abuf[buf][lds_off]             = aA0;                          \
        *(u16x8*)&Abuf[buf][lds_off + 64  * LDT] = aA1;                          \
        *(u16x8*)&Abuf[buf][lds_off + 128 * LDT] = aA2;                          \
        *(u16x8*)&Abuf[buf][lds_off + 192 * LDT] = aA3;                          \
        *(u16x8*)&Bbuf[buf][lds_off]             = bA0;                          \
        *(u16x8*)&Bbuf[buf][lds_off + 64  * LDT] = bA1; }
    #define LSTOREB_RS(buf) {                                                    \
        *(u16x8*)&Abuf[buf][lds_off]             = aB0;                          \
        *(u16x8*)&Abuf[buf][lds_off + 64  * LDT] = aB1;                          \
        *(u16x8*)&Abuf[buf][lds_off + 128 * LDT] = aB2;                          \
        *(u16x8*)&Abuf[buf][lds_off + 192 * LDT] = aB3;                          \
        *(u16x8*)&Bbuf[buf][lds_off]             = bB0;                          \
        *(u16x8*)&Bbuf[buf][lds_off + 64  * LDT] = bB1; }
    #define MFMAS_RS(buf) {                                                      \
        bf16x8 af[8], bfr[4];                                                    \
        _Pragma("unroll")                                                        \
        for (int ni = 0; ni < 4; ++ni)                                           \
            bfr[ni] = *(const bf16x8*)&Bbuf[buf][(wc + ni * 16 + lrow) * LDT + kgrp * 8]; \
        _Pragma("unroll")                                                        \
        for (int mi = 0; mi < 8; ++mi)                                           \
            af[mi] = *(const bf16x8*)&Abuf[buf][(wr + mi * 16 + lrow) * LDT + kgrp * 8]; \
        _Pragma("unroll")                                                        \
        for (int mi = 0; mi < 8; ++mi)                                           \
            _Pragma("unroll")                                                    \
            for (int ni = 0; ni < 4; ++ni)                                       \
                acc[mi][ni] = __builtin_amdgcn_mfma_f32_16x16x32_bf16(           \
                    bfr[ni], af[mi], acc[mi][ni], 0, 0, 0); }

    GLOADA_RS(0);
    GLOADB_RS(1);
    LSTOREA_RS(0);
    __syncthreads();
    #pragma unroll
    for (int kt2 = 0; kt2 < KT; kt2 += 2) {
        LSTOREB_RS(1);
        if (kt2 + 2 < KT) GLOADA_RS(kt2 + 2);
        MFMAS_RS(0);
        __syncthreads();
        if (kt2 + 2 < KT) {
            LSTOREA_RS(0);
            if (kt2 + 3 < KT) GLOADB_RS(kt2 + 3);
        }
        MFMAS_RS(1);
        if (kt2 + 2 < KT) __syncthreads();
    }
    #undef GLOADA_RS
    #undef GLOADB_RS
    #undef LSTOREA_RS
    #undef LSTOREB_RS
    #undef MFMAS_RS

    float4 bcol[4], scol[4];
    #pragma unroll
    for (int ni = 0; ni < 4; ++ni) {
        const int col0 = bn + wc + ni * 16 + (kgrp << 2);
        bcol[ni] = *(const float4*)(Bias + col0);
        if (LNEP) scol[ni] = *(const float4*)(S + col0);
    }
    const bool isQ = (bn < 256);
    float acKV[4][2] = {}, acKS[4][2] = {};
    float scal1 = 0.f;
    #pragma unroll
    for (int mi = 0; mi < 8; ++mi) {
        const int row = bm + wr + mi * 16 + lrow;
        float mrow = 0.f, rsrow = 0.f;
        if (LNEP) { mrow = mean[row]; rsrow = rstd[row]; }
        const size_t rowC = (size_t)row * ldc;
        #pragma unroll
        for (int ni = 0; ni < 4; ++ni) {
            const int col0 = bn + wc + ni * 16 + (kgrp << 2);
            float v[4];
            #pragma unroll
            for (int r = 0; r < 4; ++r) v[r] = acc[mi][ni][r];
            if (LNEP) {
                v[0] = fmaf(v[0] - mrow * scol[ni].x, rsrow, bcol[ni].x);
                v[1] = fmaf(v[1] - mrow * scol[ni].y, rsrow, bcol[ni].y);
                v[2] = fmaf(v[2] - mrow * scol[ni].z, rsrow, bcol[ni].z);
                v[3] = fmaf(v[3] - mrow * scol[ni].w, rsrow, bcol[ni].w);
            } else {
                v[0] += bcol[ni].x; v[1] += bcol[ni].y;
                v[2] += bcol[ni].z; v[3] += bcol[ni].w;
            }
            if (GELU_EP) {
                v[0] = gelu_f(v[0]); v[1] = gelu_f(v[1]);
                v[2] = gelu_f(v[2]); v[3] = gelu_f(v[3]);
            }
            if (REDUCE && !isQ) {
                acKV[ni][0] = fmaf(v[0], v[1], acKV[ni][0]);
                acKV[ni][1] = fmaf(v[2], v[3], acKV[ni][1]);
                acKS[ni][0] += v[0];
                acKS[ni][1] += v[2];
                scal1 = fmaf(v[0], v[0], fmaf(v[2], v[2], scal1));
                const unsigned int pk2 =
                    (unsigned int)f2bf(v[1]) | ((unsigned int)f2bf(v[3]) << 16);
                *(unsigned int*)(Cv + (size_t)row * HID + ((col0 - 256) >> 1)) = pk2;
            } else {
                if (REDUCE) {
                    scal1 = fmaf(v[0], v[0], fmaf(v[1], v[1],
                             fmaf(v[2], v[2], fmaf(v[3], v[3], scal1))));
                }
                if (OUTF32) {
                    float4 o = {v[0], v[1], v[2], v[3]};
                    *(float4*)((float*)C + rowC + col0) = o;
                } else {
                    bf16x4 o = {(__bf16)v[0], (__bf16)v[1], (__bf16)v[2], (__bf16)v[3]};
                    *(bf16x4*)((unsigned short*)C + rowC + col0) = o;
                }
            }
        }
    }
    if (REDUCE) {
        const int rowG = bm >> 8;
        #pragma unroll
        for (int off = 32; off > 0; off >>= 1) scal1 += __shfl_xor(scal1, off, 64);
        if (lane == 0) sredS[wv] = scal1;
        if (!isQ) {
            #pragma unroll
            for (int ni = 0; ni < 4; ++ni)
                #pragma unroll
                for (int pr = 0; pr < 2; ++pr) {
                    float a = acKV[ni][pr], b = acKS[ni][pr];
                    #pragma unroll
                    for (int off = 1; off < 16; off <<= 1) {
                        a += __shfl_xor(a, off, 64);
                        b += __shfl_xor(b, off, 64);
                    }
                    if (lrow == 0) {
                        const int p = (wc >> 1) + ni * 8 + (kgrp << 1) + pr;
                        redKV[wv >> 1][p] = a;
                        redKS[wv >> 1][p] = b;
                    }
                }
        }
        __syncthreads();
        if (tid == 0) {
            const float t = sredS[0] + sredS[1] + sredS[2] + sredS[3];
            if (isQ) psq[rowG * 2 + (bn >> 7)] = t;
            else     psk[rowG * 4 + ((bn - 256) >> 7)] = t;
        }
        if (!isQ && tid < 64) {
            const int cb = (bn - 256) >> 1;
            pkv[(size_t)rowG * 256 + cb + tid] = redKV[0][tid] + redKV[1][tid];
            pks[(size_t)rowG * 256 + cb + tid] = redKS[0][tid] + redKS[1][tid];
        }
    }
}

// ------- full-row GEMM (M=256): R20 1-deep core; ATTN staging; fused stats ----
template<int K, bool ATTN, bool STATS, bool OUTF32>
__global__ __launch_bounds__(256, 2) void gemm_rn(
    const unsigned short* __restrict__ A, const int lda,
    const unsigned short* __restrict__ Av,
    const unsigned short* __restrict__ Wt,            // [256][K]
    const float* __restrict__ Bias,
    const unsigned short* __restrict__ res,           // [.][256] bf16
    void* __restrict__ C,                             // [.][256]
    float* __restrict__ meanO, float* __restrict__ rstdO,
    const float* __restrict__ kvs, const float* __restrict__ kss,
    const float* __restrict__ scal)
{
    constexpr int KT  = K / 32;
    constexpr int LDT = 40;
    __shared__ __align__(16) unsigned short Abuf[2][128 * LDT];   // 20 KB
    __shared__ __align__(16) unsigned short Bbuf[2][256 * LDT];   // 40 KB
    __shared__ float sredS[128][2];
    __shared__ float sredQ[128][2];
    const int tid = threadIdx.x;
    const int bm  = blockIdx.x << 7;                 // 128-row tile
    const int lr = tid >> 2;
    const int lk = (tid & 3) << 3;
    const unsigned short* Ag = A  + (size_t)(bm + lr) * lda + lk;
    const unsigned short* Bg = Wt + (size_t)lr * K + lk;
    const int lds_off = lr * LDT + lk;

    const int lane = tid & 63;
    const int wv   = tid >> 6;
    const int wr   = (wv >> 1) << 6;   // 0 / 64
    const int wc   = (wv & 1) << 7;    // 0 / 128
    const int lrow = lane & 15;
    const int kgrp = lane >> 4;

    const float inv = ATTN ? scal[0] : 0.f;

    f32x4 acc[4][8];
    #pragma unroll
    for (int i = 0; i < 4; ++i)
        #pragma unroll
        for (int j = 0; j < 8; ++j)
            acc[i][j] = (f32x4){0.f, 0.f, 0.f, 0.f};

    u16x8 ra0, ra1, rb0, rb1, rb2, rb3;
    auto gload = [&](int kt) {
        const unsigned short* b = Bg + kt * 32;
        rb0 = *(const u16x8*)b;
        rb1 = *(const u16x8*)(b + (size_t)64  * K);
        rb2 = *(const u16x8*)(b + (size_t)128 * K);
        rb3 = *(const u16x8*)(b + (size_t)192 * K);
        if constexpr (ATTN) {
            const int col = kt * 32 + lk;              // head kt, cols col..col+7
            float kvsL[8], kssL[8];
            *(float4*)&kvsL[0] = *(const float4*)(kvs + col);
            *(float4*)&kvsL[4] = *(const float4*)(kvs + col + 4);
            *(float4*)&kssL[0] = *(const float4*)(kss + col);
            *(float4*)&kssL[4] = *(const float4*)(kss + col + 4);
            #pragma unroll
            for (int half = 0; half < 2; ++half) {
                const size_t rbase = (size_t)(bm + lr + half * 64) * 256;
                const u16x8 q8 = *(const u16x8*)(A  + rbase + col);
                const u16x8 v8 = *(const u16x8*)(Av + rbase + col);
                float qf[8];
                float dot = 0.f;
                #pragma unroll
                for (int j = 0; j < 8; ++j) {
                    qf[j] = bf2f(q8[j]);
                    dot = fmaf(qf[j], kssL[j], dot);
                }
                dot += __shfl_xor(dot, 1, 4);
                dot += __shfl_xor(dot, 2, 4);
                const float rden = 1.0f / fmaf(dot, inv, (float)N_TOK);
                u16x8 o;
                #pragma unroll
                for (int j = 0; j < 8; ++j)
                    o[j] = f2bf(fmaf(qf[j] * kvsL[j], inv,
                                     bf2f(v8[j]) * (float)N_TOK) * rden);
                if (half == 0) ra0 = o; else ra1 = o;
            }
        } else {
            const unsigned short* a = Ag + kt * 32;
            ra0 = *(const u16x8*)a;
            ra1 = *(const u16x8*)(a + (size_t)64 * lda);
        }
    };
    auto lstore = [&](int buf) {
        *(u16x8*)&Abuf[buf][lds_off]             = ra0;
        *(u16x8*)&Abuf[buf][lds_off + 64 * LDT]  = ra1;
        *(u16x8*)&Bbuf[buf][lds_off]             = rb0;
        *(u16x8*)&Bbuf[buf][lds_off + 64  * LDT] = rb1;
        *(u16x8*)&Bbuf[buf][lds_off + 128 * LDT] = rb2;
        *(u16x8*)&Bbuf[buf][lds_off + 192 * LDT] = rb3;
    };

    gload(0);
    lstore(0);
    __syncthreads();
    for (int kt = 0; kt < KT; ++kt) {
        const int cur = kt & 1;
        if (kt + 1 < KT) gload(kt + 1);
        bf16x8 af[4], bfr[8];
        #pragma unroll
        for (int ni = 0; ni < 8; ++ni)
            bfr[ni] = *(const bf16x8*)&Bbuf[cur][(wc + ni * 16 + lrow) * LDT + kgrp * 8];
        #pragma unroll
        for (int mi = 0; mi < 4; ++mi)
            af[mi] = *(const bf16x8*)&Abuf[cur][(wr + mi * 16 + lrow) * LDT + kgrp * 8];
        #pragma unroll
        for (int mi = 0; mi < 4; ++mi)
            #pragma unroll
            for (int ni = 0; ni < 8; ++ni)
                acc[mi][ni] = __builtin_amdgcn_mfma_f32_16x16x32_bf16(
                    bfr[ni], af[mi], acc[mi][ni], 0, 0, 0);   // C^T frags
        if (kt + 1 < KT) {
            lstore(cur ^ 1);
            __syncthreads();
        }
    }
    float sS[4], sQ[4];
    #pragma unroll
    for (int mi = 0; mi < 4; ++mi) { sS[mi] = 0.f; sQ[mi] = 0.f; }
    #pragma unroll
    for (int mi = 0; mi < 4; ++mi) {
        const int row = bm + wr + mi * 16 + lrow;
        const size_t rowC = (size_t)row * HID;
        #pragma unroll
        for (int ni = 0; ni < 8; ++ni) {
            const int col0 = wc + ni * 16 + (kgrp << 2);
            const float4 bcol = *(const float4*)(Bias + col0);
            const ushort4 rv = *(const ushort4*)(res + rowC + col0);
            float v[4];
            #pragma unroll
            for (int r = 0; r < 4; ++r) v[r] = acc[mi][ni][r];
            v[0] += bcol.x + bf2f(rv.x);
            v[1] += bcol.y + bf2f(rv.y);
            v[2] += bcol.z + bf2f(rv.z);
            v[3] += bcol.w + bf2f(rv.w);
            if (STATS) {
                sS[mi] += v[0] + v[1] + v[2] + v[3];
                sQ[mi] = fmaf(v[0], v[0], fmaf(v[1], v[1],
                          fmaf(v[2], v[2], fmaf(v[3], v[3], sQ[mi]))));
            }
            if (OUTF32) {
                float4 o = {v[0], v[1], v[2], v[3]};
                *(float4*)((float*)C + rowC + col0) = o;
            } else {
                bf16x4 o = {(__bf16)v[0], (__bf16)v[1], (__bf16)v[2], (__bf16)v[3]};
                *(bf16x4*)((unsigned short*)C + rowC + col0) = o;
            }
        }
    }
    if (STATS) {
        #pragma unroll
        for (int mi = 0; mi < 4; ++mi) {
            sS[mi] += __shfl_xor(sS[mi], 16, 64);
            sS[mi] += __shfl_xor(sS[mi], 32, 64);
            sQ[mi] += __shfl_xor(sQ[mi], 16, 64);
            sQ[mi] += __shfl_xor(sQ[mi], 32, 64);
        }
        __syncthreads();
        if (lane < 16) {
            #pragma unroll
            for (int mi = 0; mi < 4; ++mi) {
                const int ridx = wr + mi * 16 + lrow;
                sredS[ridx][wv & 1] = sS[mi];
                sredQ[ridx][wv & 1] = sQ[mi];
            }
        }
        __syncthreads();
        if ((wv & 1) == 0 && lane < 16) {
            #pragma unroll
            for (int mi = 0; mi < 4; ++mi) {
                const int ridx = wr + mi * 16 + lrow;
                const float Ssum = sredS[ridx][0] + sredS[ridx][1];
                const float Qsum = sredQ[ridx][0] + sredQ[ridx][1];
                const float m    = Ssum * (1.0f / HID);
                const float var  = fmaxf(Qsum * (1.0f / HID) - m * m, 0.f);
                meanO[bm + ridx] = m;
                rstdO[bm + ridx] = rsqrtf(var + EPS_LN);
            }
        }
    }
}

// ------- parallel finalize: 32 blocks of column sums + 1 block of scalars -----
__global__ __launch_bounds__(256) void finalize_kernel(
    const float* __restrict__ pkv, const float* __restrict__ pks,
    const float* __restrict__ psq, const float* __restrict__ psk,
    float* __restrict__ kvsum, float* __restrict__ kssum, float* __restrict__ scal)
{
    const int blk = blockIdx.x;
    const int tid = threadIdx.x;
    if (blk < 32) {
        const int col = blk * 8 + (tid >> 5);
        const int sub = tid & 31;
        float kv = 0.f, ks = 0.f;
        #pragma unroll
        for (int j = 0; j < 8; ++j) {
            const int rg = sub + (j << 5);
            kv += pkv[(size_t)rg * HID + col];
            ks += pks[(size_t)rg * HID + col];
        }
        #pragma unroll
        for (int off = 16; off > 0; off >>= 1) {
            kv += __shfl_xor(kv, off, 32);
            ks += __shfl_xor(ks, off, 32);
        }
        if (sub == 0) { kvsum[col] = kv; kssum[col] = ks; }
    } else {
        float sq = psq[tid] + psq[tid + 256];
        float sk = psk[tid] + psk[tid + 256] + psk[tid + 512] + psk[tid + 768];
        #pragma unroll
        for (int off = 32; off > 0; off >>= 1) {
            sq += __shfl_xor(sq, off, 64);
            sk += __shfl_xor(sk, off, 64);
        }
        __shared__ float s1[4], s2[4];
        if ((tid & 63) == 0) { s1[tid >> 6] = sq; s2[tid >> 6] = sk; }
        __syncthreads();
        if (tid == 0) {
            const float SQ = s1[0] + s1[1] + s1[2] + s1[3];
            const float SK = s2[0] + s2[1] + s2[2] + s2[3];
            scal[0] = rsqrtf(SQ * SK);
        }
    }
}

extern "C" void kernel_launch(void* const* d_in, const int* in_sizes, int n_in,
                              void* d_out, int out_size, void* d_ws, size_t ws_size,
                              hipStream_t stream) {
    const float* x    = (const float*)d_in[0];
    const float* Wq   = (const float*)d_in[1];
    const float* bq   = (const float*)d_in[2];
    const float* Wk   = (const float*)d_in[3];
    const float* bk   = (const float*)d_in[4];
    const float* Wv   = (const float*)d_in[5];
    const float* bv   = (const float*)d_in[6];
    const float* Wh   = (const float*)d_in[7];
    const float* bh   = (const float*)d_in[8];
    const float* g1kv = (const float*)d_in[9];
    const float* b1kv = (const float*)d_in[10];
    const float* g1q  = (const float*)d_in[11];
    const float* b1q  = (const float*)d_in[12];
    const float* Wf1  = (const float*)d_in[13];
    const float* bf1  = (const float*)d_in[14];
    const float* Wf2  = (const float*)d_in[15];
    const float* bf2  = (const float*)d_in[16];
    const float* g2   = (const float*)d_in[17];
    const float* b2   = (const float*)d_in[18];
    float* out = (float*)d_out;

    // ---- workspace (~200 MiB; limit ~256 MiB) ----
    char* p = (char*)d_ws;
    const size_t nh = (size_t)N_TOK * HID;
    unsigned short* hb   = (unsigned short*)p; p += nh * 2;       // 32 MiB
    unsigned short* hpre = (unsigned short*)p; p += nh * 2;       // 32 MiB
    unsigned short* act  = (unsigned short*)p;                    // 128 MiB
    unsigned short* qbuf = act;                                   // overlay 32 MiB
    unsigned short* vbuf = act + nh;                              // overlay 32 MiB
    p += nh * 8;
    float* meanb = (float*)p; p += N_TOK * sizeof(float);
    float* rstdb = (float*)p; p += N_TOK * sizeof(float);
    unsigned short* wtqkv = (unsigned short*)p; p += (size_t)3 * QKVM * HID * 2;
    unsigned short* wth   = (unsigned short*)p; p += (size_t)3 * HID * HID * 2;
    unsigned short* wtf1  = (unsigned short*)p; p += (size_t)3 * FFDIM * HID * 2;
    unsigned short* wtf2  = (unsigned short*)p; p += (size_t)3 * HID * FFDIM * 2;
    float* bqkv = (float*)p; p += (size_t)3 * QKVM * sizeof(float);
    float* bf1f = (float*)p; p += (size_t)3 * FFDIM * sizeof(float);
    float* Sqkv = (float*)p; p += (size_t)3 * QKVM * sizeof(float);
    float* Sf1  = (float*)p; p += (size_t)3 * FFDIM * sizeof(float);
    float* pkv  = (float*)p; p += (size_t)256 * HID * sizeof(float);
    float* pks  = (float*)p; p += (size_t)256 * HID * sizeof(float);
    float* psq  = (float*)p; p += 512 * sizeof(float);
    float* psk  = (float*)p; p += 1024 * sizeof(float);
    float* kvs  = (float*)p; p += HID * sizeof(float);
    float* kss  = (float*)p; p += HID * sizeof(float);
    float* scal = (float*)p; p += 256;

    // ---- prep: q cols 0..255; k at 256+2j; v at 257+2j (interleaved) ----
    const size_t qkvLS = (size_t)QKVM * HID;
    wconv<<<dim3(8, 8, 3),  256, 0, stream>>>(Wq,  g1q,  wtqkv, HID, HID, qkvLS, 0,   1);
    wconv<<<dim3(8, 8, 3),  256, 0, stream>>>(Wk,  g1kv, wtqkv, HID, HID, qkvLS, 256, 2);
    wconv<<<dim3(8, 8, 3),  256, 0, stream>>>(Wv,  g1kv, wtqkv, HID, HID, qkvLS, 257, 2);
    wconv<<<dim3(8, 8, 3),  256, 0, stream>>>(Wh,  nullptr, wth, HID, HID, (size_t)HID * HID, 0, 1);
    wconv<<<dim3(8, 32, 3), 256, 0, stream>>>(Wf1, g2,   wtf1, HID, FFDIM, (size_t)FFDIM * HID, 0, 1);
    wconv<<<dim3(32, 8, 3), 256, 0, stream>>>(Wf2, nullptr, wtf2, FFDIM, HID, (size_t)HID * FFDIM, 0, 1);
    colsum<<<dim3(3, 3), 256, 0, stream>>>(wtqkv, Sqkv, QKVM);
    colsum<<<dim3(4, 3), 256, 0, stream>>>(wtf1,  Sf1,  FFDIM);
    biasfold<<<dim3(1, 3), 256, 0, stream>>>(Wq,  bq,  b1q,  bqkv, HID, HID, QKVM, 0,   1);
    biasfold<<<dim3(1, 3), 256, 0, stream>>>(Wk,  bk,  b1kv, bqkv, HID, HID, QKVM, 256, 2);
    biasfold<<<dim3(1, 3), 256, 0, stream>>>(Wv,  bv,  b1kv, bqkv, HID, HID, QKVM, 257, 2);
    biasfold<<<dim3(4, 3), 256, 0, stream>>>(Wf1, bf1, b2,   bf1f, HID, FFDIM, FFDIM, 0, 1);
    cast_stats<<<N_TOK / 4, 256, 0, stream>>>(x, hb, meanb, rstdb);

    const int gQKV = (N_TOK / 256) * (QKVM / 128);   // 1536
    const int gRN  = N_TOK / 128;                    // 512 (full-row H GEMM)
    const int gF1  = (N_TOK / 256) * (FFDIM / 256);  // 1024 (2-phase, 256x256)
    const int gF2  = N_TOK / 256;                    // 256  (2-phase, full-row)

    for (int l = 0; l < 3; ++l) {
        // QKV: epilogue-LN + fused attention reduction -> qbuf/vbuf + partials
        gemm_rs<HID, true, false, true, false><<<gQKV, 256, 0, stream>>>(
            hb, HID, wtqkv + l * qkvLS, bqkv + l * QKVM, Sqkv + l * QKVM,
            meanb, rstdb, qbuf, HID, QKVM / 128, vbuf, pkv, pks, psq, psk);
        finalize_kernel<<<33, 256, 0, stream>>>(pkv, pks, psq, psk, kvs, kss, scal);
        // H (full-row, ATTN-fused A): attn(q,v) @ Wh + bh + hb -> hpre + stats
        gemm_rn<HID, true, true, false><<<gRN, 256, 0, stream>>>(
            qbuf, HID, vbuf, wth + (size_t)l * HID * HID, bh + (size_t)l * HID,
            hb, hpre, meanb, rstdb, kvs, kss, scal);
        // FFN1 (2-phase 256x256): epilogue-LN + GELU -> act (uses hpre stats)
        gemm_2p<HID, true, true, false, false, false><<<gF1, 512, 0, stream>>>(
            hpre, HID, wtf1 + (size_t)l * FFDIM * HID, bf1f + (size_t)l * FFDIM,
            Sf1 + (size_t)l * FFDIM, meanb, rstdb, nullptr, act, FFDIM, 4,
            nullptr, nullptr);
        // FFN2 (2-phase full-row): + res(hpre) -> next hb (+stats) or final out
        if (l < 2)
            gemm_2p<FFDIM, false, false, true, true, false><<<gF2, 512, 0, stream>>>(
                act, FFDIM, wtf2 + (size_t)l * HID * FFDIM, bf2 + (size_t)l * HID,
                nullptr, nullptr, nullptr, hpre, hb, HID, 1, meanb, rstdb);
        else
            gemm_2p<FFDIM, false, false, true, false, true><<<gF2, 512, 0, stream>>>(
                act, FFDIM, wtf2 + (size_t)l * HID * FFDIM, bf2 + (size_t)l * HID,
                nullptr, nullptr, nullptr, hpre, out, HID, 1, nullptr, nullptr);
    }
}

// Round 24
// 925.718 us; speedup vs baseline: 1.0464x; 1.0464x over previous
//
#include <hip/hip_runtime.h>
#include <math.h>

#define N_TOK 65536
#define HID   256
#define FFDIM 1024
#define QKVM  768
#define EPS_LN 1e-5f

typedef __bf16 bf16x8 __attribute__((ext_vector_type(8)));
typedef __bf16 bf16x4 __attribute__((ext_vector_type(4)));
typedef float  f32x4  __attribute__((ext_vector_type(4)));
typedef unsigned short u16x8 __attribute__((ext_vector_type(8)));

// tanh-form GELU: x * sigmoid(1.59577*x*(1+0.044715*x^2)); |err| <= ~2e-3
__device__ __forceinline__ float gelu_f(float x) {
    const float t = 1.59576912f * x * fmaf(0.044715f, x * x, 1.0f);
    return x / (1.0f + __expf(-t));
}
__device__ __forceinline__ float bf2f(unsigned short u) {
    return __uint_as_float(((unsigned int)u) << 16);
}
__device__ __forceinline__ unsigned short f2bf(float f) {
    unsigned int x = __float_as_uint(f);
    unsigned int r = ((x >> 16) & 1u) + 0x7fffu;
    return (unsigned short)((x + r) >> 16);
}

// -- weight fp32 [L,K,M] -> bf16 transposed [L][moff + m*mstride][K], g-scaled
__global__ __launch_bounds__(256) void wconv(
    const float* __restrict__ src, const float* __restrict__ g,
    unsigned short* __restrict__ dst,
    const int K, const int M, const size_t dstLS, const int moff, const int mstride)
{
    const int l = blockIdx.z;
    __shared__ float t[32][33];
    const int r  = threadIdx.x >> 3;
    const int c0 = (threadIdx.x & 7) * 4;
    const int bk = blockIdx.x * 32;
    const int bm = blockIdx.y * 32;
    float4 v4 = *(const float4*)(src + (size_t)l * K * M + (size_t)(bk + r) * M + bm + c0);
    if (g) {
        const float gv = g[(size_t)l * K + bk + r];
        v4.x *= gv; v4.y *= gv; v4.z *= gv; v4.w *= gv;
    }
    t[r][c0] = v4.x; t[r][c0+1] = v4.y; t[r][c0+2] = v4.z; t[r][c0+3] = v4.w;
    __syncthreads();
    ushort4 o;
    o.x = f2bf(t[c0+0][r]);
    o.y = f2bf(t[c0+1][r]);
    o.z = f2bf(t[c0+2][r]);
    o.w = f2bf(t[c0+3][r]);
    *(ushort4*)(dst + (size_t)l * dstLS +
                (size_t)(moff + (bm + r) * mstride) * K + bk + c0) = o;
}

__global__ __launch_bounds__(256) void biasfold(
    const float* __restrict__ W, const float* __restrict__ bias,
    const float* __restrict__ bvec, float* __restrict__ outb,
    const int K, const int M, const size_t outLS, const int moff, const int mstride)
{
    const int l = blockIdx.y;
    const int m = blockIdx.x * 256 + threadIdx.x;
    float acc = bias[(size_t)l * M + m];
    const float* Wl = W + (size_t)l * K * M;
    const float* bv = bvec + (size_t)l * K;
    for (int k = 0; k < K; ++k) acc = fmaf(bv[k], Wl[(size_t)k * M + m], acc);
    outb[(size_t)l * outLS + moff + m * mstride] = acc;
}

__global__ __launch_bounds__(256) void colsum(
    const unsigned short* __restrict__ wt, float* __restrict__ S, const int M)
{
    const int l = blockIdx.y;
    const int j = blockIdx.x * 256 + threadIdx.x;
    const unsigned short* rowp = wt + (size_t)l * M * HID + (size_t)j * HID;
    float s = 0.f;
    for (int k = 0; k < HID; k += 8) {
        const u16x8 u = *(const u16x8*)(rowp + k);
        #pragma unroll
        for (int t = 0; t < 8; ++t) s += bf2f(u[t]);
    }
    S[(size_t)l * M + j] = s;
}

// ------- fp32 -> bf16 cast + fused row stats ---------------------------------
__global__ __launch_bounds__(256) void cast_stats(
    const float* __restrict__ x, unsigned short* __restrict__ hb,
    float* __restrict__ mean, float* __restrict__ rstd)
{
    const int row  = blockIdx.x * 4 + (threadIdx.x >> 6);
    const int lane = threadIdx.x & 63;
    const size_t base = (size_t)row * HID + lane * 4;
    const float4 xv = *(const float4*)(x + base);
    ushort4 o;
    o.x = f2bf(xv.x); o.y = f2bf(xv.y); o.z = f2bf(xv.z); o.w = f2bf(xv.w);
    *(ushort4*)(hb + base) = o;
    float s  = xv.x + xv.y + xv.z + xv.w;
    float s2 = fmaf(xv.x, xv.x, fmaf(xv.y, xv.y, fmaf(xv.z, xv.z, xv.w * xv.w)));
    #pragma unroll
    for (int off = 32; off > 0; off >>= 1) {
        s  += __shfl_xor(s, off, 64);
        s2 += __shfl_xor(s2, off, 64);
    }
    if (lane == 0) {
        const float m   = s * (1.0f / HID);
        const float var = fmaxf(s2 * (1.0f / HID) - m * m, 0.f);
        mean[row] = m;
        rstd[row] = rsqrtf(var + EPS_LN);
    }
}

// ------- 256x128-tile GEMM + 2-deep reg prefetch: LN-ep, GELU, fused reduce ---
template<int K, bool LNEP, bool GELU_EP, bool REDUCE, bool OUTF32>
__global__ __launch_bounds__(256, 2) void gemm_rs(
    const unsigned short* __restrict__ A, const int lda,
    const unsigned short* __restrict__ Wt,
    const float* __restrict__ Bias, const float* __restrict__ S,
    const float* __restrict__ mean, const float* __restrict__ rstd,
    void* __restrict__ C, const int ldc, const int nCT,
    unsigned short* __restrict__ Cv,
    float* __restrict__ pkv, float* __restrict__ pks,
    float* __restrict__ psq, float* __restrict__ psk)
{
    constexpr int KT  = K / 32;          // 8 (even)
    constexpr int LDT = 40;
    __shared__ __align__(16) unsigned short Abuf[2][256 * LDT];   // 40 KB
    __shared__ __align__(16) unsigned short Bbuf[2][128 * LDT];   // 20 KB
    __shared__ float redKV[2][64];
    __shared__ float redKS[2][64];
    __shared__ float sredS[4];
    const int tid = threadIdx.x;
    const int gsz = nCT << 3;
    const int grp = blockIdx.x / gsz;
    const int rem = blockIdx.x - grp * gsz;
    const int bm  = ((grp << 3) + (rem & 7)) << 8;   // 256-row tile (fastest)
    const int bn  = (rem >> 3) << 7;                 // 128-col tile
    const int lr = tid >> 2;
    const int lk = (tid & 3) << 3;
    const unsigned short* Ag = A  + (size_t)(bm + lr) * lda + lk;
    const unsigned short* Bg = Wt + (size_t)(bn + lr) * K   + lk;
    const int lds_off = lr * LDT + lk;

    const int lane = tid & 63;
    const int wv   = tid >> 6;
    const int wr   = (wv >> 1) << 7;   // 0 / 128
    const int wc   = (wv & 1) << 6;    // 0 / 64
    const int lrow = lane & 15;
    const int kgrp = lane >> 4;

    f32x4 acc[8][4];
    #pragma unroll
    for (int i = 0; i < 8; ++i)
        #pragma unroll
        for (int j = 0; j < 4; ++j)
            acc[i][j] = (f32x4){0.f, 0.f, 0.f, 0.f};

    // two named register sets (2-deep prefetch; static indexing per rule #20)
    u16x8 aA0, aA1, aA2, aA3, bA0, bA1;
    u16x8 aB0, aB1, aB2, aB3, bB0, bB1;
    #define GLOADA_RS(kt) { const unsigned short* a_ = Ag + (kt) * 32;           \
        const unsigned short* b_ = Bg + (kt) * 32;                               \
        aA0 = *(const u16x8*)a_;                                                 \
        aA1 = *(const u16x8*)(a_ + (size_t)64  * lda);                           \
        aA2 = *(const u16x8*)(a_ + (size_t)128 * lda);                           \
        aA3 = *(const u16x8*)(a_ + (size_t)192 * lda);                           \
        bA0 = *(const u16x8*)b_;                                                 \
        bA1 = *(const u16x8*)(b_ + (size_t)64 * K); }
    #define GLOADB_RS(kt) { const unsigned short* a_ = Ag + (kt) * 32;           \
        const unsigned short* b_ = Bg + (kt) * 32;                               \
        aB0 = *(const u16x8*)a_;                                                 \
        aB1 = *(const u16x8*)(a_ + (size_t)64  * lda);                           \
        aB2 = *(const u16x8*)(a_ + (size_t)128 * lda);                           \
        aB3 = *(const u16x8*)(a_ + (size_t)192 * lda);                           \
        bB0 = *(const u16x8*)b_;                                                 \
        bB1 = *(const u16x8*)(b_ + (size_t)64 * K); }
    #define LSTOREA_RS(buf) {                                                    \
        *(u16x8*)&Abuf[buf][lds_off]             = aA0;                          \
        *(u16x8*)&Abuf[buf][lds_off + 64  * LDT] = aA1;                          \
        *(u16x8*)&Abuf[buf][lds_off + 128 * LDT] = aA2;                          \
        *(u16x8*)&Abuf[buf][lds_off + 192 * LDT] = aA3;                          \
        *(u16x8*)&Bbuf[buf][lds_off]             = bA0;                          \
        *(u16x8*)&Bbuf[buf][lds_off + 64  * LDT] = bA1; }
    #define LSTOREB_RS(buf) {                                                    \
        *(u16x8*)&Abuf[buf][lds_off]             = aB0;                          \
        *(u16x8*)&Abuf[buf][lds_off + 64  * LDT] = aB1;                          \
        *(u16x8*)&Abuf[buf][lds_off + 128 * LDT] = aB2;                          \
        *(u16x8*)&Abuf[buf][lds_off + 192 * LDT] = aB3;                          \
        *(u16x8*)&Bbuf[buf][lds_off]             = bB0;                          \
        *(u16x8*)&Bbuf[buf][lds_off + 64  * LDT] = bB1; }
    #define MFMAS_RS(buf) {                                                      \
        bf16x8 af[8], bfr[4];                                                    \
        _Pragma("unroll")                                                        \
        for (int ni = 0; ni < 4; ++ni)                                           \
            bfr[ni] = *(const bf16x8*)&Bbuf[buf][(wc + ni * 16 + lrow) * LDT + kgrp * 8]; \
        _Pragma("unroll")                                                        \
        for (int mi = 0; mi < 8; ++mi)                                           \
            af[mi] = *(const bf16x8*)&Abuf[buf][(wr + mi * 16 + lrow) * LDT + kgrp * 8]; \
        _Pragma("unroll")                                                        \
        for (int mi = 0; mi < 8; ++mi)                                           \
            _Pragma("unroll")                                                    \
            for (int ni = 0; ni < 4; ++ni)                                       \
                acc[mi][ni] = __builtin_amdgcn_mfma_f32_16x16x32_bf16(           \
                    bfr[ni], af[mi], acc[mi][ni], 0, 0, 0); }

    GLOADA_RS(0);
    GLOADB_RS(1);
    LSTOREA_RS(0);
    __syncthreads();
    #pragma unroll
    for (int kt2 = 0; kt2 < KT; kt2 += 2) {
        LSTOREB_RS(1);                         // loads >=2 phases old
        if (kt2 + 2 < KT) GLOADA_RS(kt2 + 2);
        MFMAS_RS(0);
        __syncthreads();
        if (kt2 + 2 < KT) {
            LSTOREA_RS(0);
            if (kt2 + 3 < KT) GLOADB_RS(kt2 + 3);
        }
        MFMAS_RS(1);
        if (kt2 + 2 < KT) __syncthreads();
    }
    #undef GLOADA_RS
    #undef GLOADB_RS
    #undef LSTOREA_RS
    #undef LSTOREB_RS
    #undef MFMAS_RS

    float4 bcol[4], scol[4];
    #pragma unroll
    for (int ni = 0; ni < 4; ++ni) {
        const int col0 = bn + wc + ni * 16 + (kgrp << 2);
        bcol[ni] = *(const float4*)(Bias + col0);
        if (LNEP) scol[ni] = *(const float4*)(S + col0);
    }
    const bool isQ = (bn < 256);
    float acKV[4][2] = {}, acKS[4][2] = {};
    float scal1 = 0.f;
    #pragma unroll
    for (int mi = 0; mi < 8; ++mi) {
        const int row = bm + wr + mi * 16 + lrow;
        float mrow = 0.f, rsrow = 0.f;
        if (LNEP) { mrow = mean[row]; rsrow = rstd[row]; }
        const size_t rowC = (size_t)row * ldc;
        #pragma unroll
        for (int ni = 0; ni < 4; ++ni) {
            const int col0 = bn + wc + ni * 16 + (kgrp << 2);
            float v[4];
            #pragma unroll
            for (int r = 0; r < 4; ++r) v[r] = acc[mi][ni][r];
            if (LNEP) {
                v[0] = fmaf(v[0] - mrow * scol[ni].x, rsrow, bcol[ni].x);
                v[1] = fmaf(v[1] - mrow * scol[ni].y, rsrow, bcol[ni].y);
                v[2] = fmaf(v[2] - mrow * scol[ni].z, rsrow, bcol[ni].z);
                v[3] = fmaf(v[3] - mrow * scol[ni].w, rsrow, bcol[ni].w);
            } else {
                v[0] += bcol[ni].x; v[1] += bcol[ni].y;
                v[2] += bcol[ni].z; v[3] += bcol[ni].w;
            }
            if (GELU_EP) {
                v[0] = gelu_f(v[0]); v[1] = gelu_f(v[1]);
                v[2] = gelu_f(v[2]); v[3] = gelu_f(v[3]);
            }
            if (REDUCE && !isQ) {
                acKV[ni][0] = fmaf(v[0], v[1], acKV[ni][0]);
                acKV[ni][1] = fmaf(v[2], v[3], acKV[ni][1]);
                acKS[ni][0] += v[0];
                acKS[ni][1] += v[2];
                scal1 = fmaf(v[0], v[0], fmaf(v[2], v[2], scal1));
                const unsigned int pk2 =
                    (unsigned int)f2bf(v[1]) | ((unsigned int)f2bf(v[3]) << 16);
                *(unsigned int*)(Cv + (size_t)row * HID + ((col0 - 256) >> 1)) = pk2;
            } else {
                if (REDUCE) {
                    scal1 = fmaf(v[0], v[0], fmaf(v[1], v[1],
                             fmaf(v[2], v[2], fmaf(v[3], v[3], scal1))));
                }
                if (OUTF32) {
                    float4 o = {v[0], v[1], v[2], v[3]};
                    *(float4*)((float*)C + rowC + col0) = o;
                } else {
                    bf16x4 o = {(__bf16)v[0], (__bf16)v[1], (__bf16)v[2], (__bf16)v[3]};
                    *(bf16x4*)((unsigned short*)C + rowC + col0) = o;
                }
            }
        }
    }
    if (REDUCE) {
        const int rowG = bm >> 8;
        #pragma unroll
        for (int off = 32; off > 0; off >>= 1) scal1 += __shfl_xor(scal1, off, 64);
        if (lane == 0) sredS[wv] = scal1;
        if (!isQ) {
            #pragma unroll
            for (int ni = 0; ni < 4; ++ni)
                #pragma unroll
                for (int pr = 0; pr < 2; ++pr) {
                    float a = acKV[ni][pr], b = acKS[ni][pr];
                    #pragma unroll
                    for (int off = 1; off < 16; off <<= 1) {
                        a += __shfl_xor(a, off, 64);
                        b += __shfl_xor(b, off, 64);
                    }
                    if (lrow == 0) {
                        const int p = (wc >> 1) + ni * 8 + (kgrp << 1) + pr;
                        redKV[wv >> 1][p] = a;
                        redKS[wv >> 1][p] = b;
                    }
                }
        }
        __syncthreads();
        if (tid == 0) {
            const float t = sredS[0] + sredS[1] + sredS[2] + sredS[3];
            if (isQ) psq[rowG * 2 + (bn >> 7)] = t;
            else     psk[rowG * 4 + ((bn - 256) >> 7)] = t;
        }
        if (!isQ && tid < 64) {
            const int cb = (bn - 256) >> 1;
            pkv[(size_t)rowG * 256 + cb + tid] = redKV[0][tid] + redKV[1][tid];
            pks[(size_t)rowG * 256 + cb + tid] = redKS[0][tid] + redKS[1][tid];
        }
    }
}

// ------- full-row GEMM (M=256): R20 1-deep core; ATTN staging; fused stats ----
template<int K, bool ATTN, bool STATS, bool OUTF32>
__global__ __launch_bounds__(256, 2) void gemm_rn(
    const unsigned short* __restrict__ A, const int lda,
    const unsigned short* __restrict__ Av,
    const unsigned short* __restrict__ Wt,            // [256][K]
    const float* __restrict__ Bias,
    const unsigned short* __restrict__ res,           // [.][256] bf16
    void* __restrict__ C,                             // [.][256]
    float* __restrict__ meanO, float* __restrict__ rstdO,
    const float* __restrict__ kvs, const float* __restrict__ kss,
    const float* __restrict__ scal)
{
    constexpr int KT  = K / 32;
    constexpr int LDT = 40;
    __shared__ __align__(16) unsigned short Abuf[2][128 * LDT];   // 20 KB
    __shared__ __align__(16) unsigned short Bbuf[2][256 * LDT];   // 40 KB
    __shared__ float sredS[128][2];
    __shared__ float sredQ[128][2];
    const int tid = threadIdx.x;
    const int bm  = blockIdx.x << 7;                 // 128-row tile
    const int lr = tid >> 2;
    const int lk = (tid & 3) << 3;
    const unsigned short* Ag = A  + (size_t)(bm + lr) * lda + lk;
    const unsigned short* Bg = Wt + (size_t)lr * K + lk;
    const int lds_off = lr * LDT + lk;

    const int lane = tid & 63;
    const int wv   = tid >> 6;
    const int wr   = (wv >> 1) << 6;   // 0 / 64
    const int wc   = (wv & 1) << 7;    // 0 / 128
    const int lrow = lane & 15;
    const int kgrp = lane >> 4;

    const float inv = ATTN ? scal[0] : 0.f;

    f32x4 acc[4][8];
    #pragma unroll
    for (int i = 0; i < 4; ++i)
        #pragma unroll
        for (int j = 0; j < 8; ++j)
            acc[i][j] = (f32x4){0.f, 0.f, 0.f, 0.f};

    u16x8 ra0, ra1, rb0, rb1, rb2, rb3;
    auto gload = [&](int kt) {
        const unsigned short* b = Bg + kt * 32;
        rb0 = *(const u16x8*)b;
        rb1 = *(const u16x8*)(b + (size_t)64  * K);
        rb2 = *(const u16x8*)(b + (size_t)128 * K);
        rb3 = *(const u16x8*)(b + (size_t)192 * K);
        if constexpr (ATTN) {
            const int col = kt * 32 + lk;              // head kt, cols col..col+7
            float kvsL[8], kssL[8];
            *(float4*)&kvsL[0] = *(const float4*)(kvs + col);
            *(float4*)&kvsL[4] = *(const float4*)(kvs + col + 4);
            *(float4*)&kssL[0] = *(const float4*)(kss + col);
            *(float4*)&kssL[4] = *(const float4*)(kss + col + 4);
            #pragma unroll
            for (int half = 0; half < 2; ++half) {
                const size_t rbase = (size_t)(bm + lr + half * 64) * 256;
                const u16x8 q8 = *(const u16x8*)(A  + rbase + col);
                const u16x8 v8 = *(const u16x8*)(Av + rbase + col);
                float qf[8];
                float dot = 0.f;
                #pragma unroll
                for (int j = 0; j < 8; ++j) {
                    qf[j] = bf2f(q8[j]);
                    dot = fmaf(qf[j], kssL[j], dot);
                }
                dot += __shfl_xor(dot, 1, 4);          // quad = one head's 32 cols
                dot += __shfl_xor(dot, 2, 4);
                const float rden = 1.0f / fmaf(dot, inv, (float)N_TOK);
                u16x8 o;
                #pragma unroll
                for (int j = 0; j < 8; ++j)
                    o[j] = f2bf(fmaf(qf[j] * kvsL[j], inv,
                                     bf2f(v8[j]) * (float)N_TOK) * rden);
                if (half == 0) ra0 = o; else ra1 = o;
            }
        } else {
            const unsigned short* a = Ag + kt * 32;
            ra0 = *(const u16x8*)a;
            ra1 = *(const u16x8*)(a + (size_t)64 * lda);
        }
    };
    auto lstore = [&](int buf) {
        *(u16x8*)&Abuf[buf][lds_off]             = ra0;
        *(u16x8*)&Abuf[buf][lds_off + 64 * LDT]  = ra1;
        *(u16x8*)&Bbuf[buf][lds_off]             = rb0;
        *(u16x8*)&Bbuf[buf][lds_off + 64  * LDT] = rb1;
        *(u16x8*)&Bbuf[buf][lds_off + 128 * LDT] = rb2;
        *(u16x8*)&Bbuf[buf][lds_off + 192 * LDT] = rb3;
    };

    gload(0);
    lstore(0);
    __syncthreads();
    for (int kt = 0; kt < KT; ++kt) {
        const int cur = kt & 1;
        if (kt + 1 < KT) gload(kt + 1);
        bf16x8 af[4], bfr[8];
        #pragma unroll
        for (int ni = 0; ni < 8; ++ni)
            bfr[ni] = *(const bf16x8*)&Bbuf[cur][(wc + ni * 16 + lrow) * LDT + kgrp * 8];
        #pragma unroll
        for (int mi = 0; mi < 4; ++mi)
            af[mi] = *(const bf16x8*)&Abuf[cur][(wr + mi * 16 + lrow) * LDT + kgrp * 8];
        #pragma unroll
        for (int mi = 0; mi < 4; ++mi)
            #pragma unroll
            for (int ni = 0; ni < 8; ++ni)
                acc[mi][ni] = __builtin_amdgcn_mfma_f32_16x16x32_bf16(
                    bfr[ni], af[mi], acc[mi][ni], 0, 0, 0);   // C^T frags
        if (kt + 1 < KT) {
            lstore(cur ^ 1);
            __syncthreads();
        }
    }
    float sS[4], sQ[4];
    #pragma unroll
    for (int mi = 0; mi < 4; ++mi) { sS[mi] = 0.f; sQ[mi] = 0.f; }
    #pragma unroll
    for (int mi = 0; mi < 4; ++mi) {
        const int row = bm + wr + mi * 16 + lrow;
        const size_t rowC = (size_t)row * HID;
        #pragma unroll
        for (int ni = 0; ni < 8; ++ni) {
            const int col0 = wc + ni * 16 + (kgrp << 2);
            const float4 bcol = *(const float4*)(Bias + col0);
            const ushort4 rv = *(const ushort4*)(res + rowC + col0);
            float v[4];
            #pragma unroll
            for (int r = 0; r < 4; ++r) v[r] = acc[mi][ni][r];
            v[0] += bcol.x + bf2f(rv.x);
            v[1] += bcol.y + bf2f(rv.y);
            v[2] += bcol.z + bf2f(rv.z);
            v[3] += bcol.w + bf2f(rv.w);
            if (STATS) {
                sS[mi] += v[0] + v[1] + v[2] + v[3];
                sQ[mi] = fmaf(v[0], v[0], fmaf(v[1], v[1],
                          fmaf(v[2], v[2], fmaf(v[3], v[3], sQ[mi]))));
            }
            if (OUTF32) {
                float4 o = {v[0], v[1], v[2], v[3]};
                *(float4*)((float*)C + rowC + col0) = o;
            } else {
                bf16x4 o = {(__bf16)v[0], (__bf16)v[1], (__bf16)v[2], (__bf16)v[3]};
                *(bf16x4*)((unsigned short*)C + rowC + col0) = o;
            }
        }
    }
    if (STATS) {
        #pragma unroll
        for (int mi = 0; mi < 4; ++mi) {
            sS[mi] += __shfl_xor(sS[mi], 16, 64);
            sS[mi] += __shfl_xor(sS[mi], 32, 64);
            sQ[mi] += __shfl_xor(sQ[mi], 16, 64);
            sQ[mi] += __shfl_xor(sQ[mi], 32, 64);
        }
        __syncthreads();
        if (lane < 16) {
            #pragma unroll
            for (int mi = 0; mi < 4; ++mi) {
                const int ridx = wr + mi * 16 + lrow;
                sredS[ridx][wv & 1] = sS[mi];
                sredQ[ridx][wv & 1] = sQ[mi];
            }
        }
        __syncthreads();
        if ((wv & 1) == 0 && lane < 16) {
            #pragma unroll
            for (int mi = 0; mi < 4; ++mi) {
                const int ridx = wr + mi * 16 + lrow;
                const float Ssum = sredS[ridx][0] + sredS[ridx][1];
                const float Qsum = sredQ[ridx][0] + sredQ[ridx][1];
                const float m    = Ssum * (1.0f / HID);
                const float var  = fmaxf(Qsum * (1.0f / HID) - m * m, 0.f);
                meanO[bm + ridx] = m;
                rstdO[bm + ridx] = rsqrtf(var + EPS_LN);
            }
        }
    }
}

// ------- parallel finalize: 32 blocks of column sums + 1 block of scalars -----
__global__ __launch_bounds__(256) void finalize_kernel(
    const float* __restrict__ pkv, const float* __restrict__ pks,
    const float* __restrict__ psq, const float* __restrict__ psk,
    float* __restrict__ kvsum, float* __restrict__ kssum, float* __restrict__ scal)
{
    const int blk = blockIdx.x;
    const int tid = threadIdx.x;
    if (blk < 32) {
        const int col = blk * 8 + (tid >> 5);
        const int sub = tid & 31;
        float kv = 0.f, ks = 0.f;
        #pragma unroll
        for (int j = 0; j < 8; ++j) {
            const int rg = sub + (j << 5);
            kv += pkv[(size_t)rg * HID + col];
            ks += pks[(size_t)rg * HID + col];
        }
        #pragma unroll
        for (int off = 16; off > 0; off >>= 1) {
            kv += __shfl_xor(kv, off, 32);
            ks += __shfl_xor(ks, off, 32);
        }
        if (sub == 0) { kvsum[col] = kv; kssum[col] = ks; }
    } else {
        float sq = psq[tid] + psq[tid + 256];
        float sk = psk[tid] + psk[tid + 256] + psk[tid + 512] + psk[tid + 768];
        #pragma unroll
        for (int off = 32; off > 0; off >>= 1) {
            sq += __shfl_xor(sq, off, 64);
            sk += __shfl_xor(sk, off, 64);
        }
        __shared__ float s1[4], s2[4];
        if ((tid & 63) == 0) { s1[tid >> 6] = sq; s2[tid >> 6] = sk; }
        __syncthreads();
        if (tid == 0) {
            const float SQ = s1[0] + s1[1] + s1[2] + s1[3];
            const float SK = s2[0] + s2[1] + s2[2] + s2[3];
            scal[0] = rsqrtf(SQ * SK);
        }
    }
}

extern "C" void kernel_launch(void* const* d_in, const int* in_sizes, int n_in,
                              void* d_out, int out_size, void* d_ws, size_t ws_size,
                              hipStream_t stream) {
    const float* x    = (const float*)d_in[0];
    const float* Wq   = (const float*)d_in[1];
    const float* bq   = (const float*)d_in[2];
    const float* Wk   = (const float*)d_in[3];
    const float* bk   = (const float*)d_in[4];
    const float* Wv   = (const float*)d_in[5];
    const float* bv   = (const float*)d_in[6];
    const float* Wh   = (const float*)d_in[7];
    const float* bh   = (const float*)d_in[8];
    const float* g1kv = (const float*)d_in[9];
    const float* b1kv = (const float*)d_in[10];
    const float* g1q  = (const float*)d_in[11];
    const float* b1q  = (const float*)d_in[12];
    const float* Wf1  = (const float*)d_in[13];
    const float* bf1  = (const float*)d_in[14];
    const float* Wf2  = (const float*)d_in[15];
    const float* bf2  = (const float*)d_in[16];
    const float* g2   = (const float*)d_in[17];
    const float* b2   = (const float*)d_in[18];
    float* out = (float*)d_out;

    // ---- workspace (~200 MiB; limit ~256 MiB) ----
    char* p = (char*)d_ws;
    const size_t nh = (size_t)N_TOK * HID;
    unsigned short* hb   = (unsigned short*)p; p += nh * 2;       // 32 MiB
    unsigned short* hpre = (unsigned short*)p; p += nh * 2;       // 32 MiB
    unsigned short* act  = (unsigned short*)p;                    // 128 MiB
    unsigned short* qbuf = act;                                   // overlay 32 MiB
    unsigned short* vbuf = act + nh;                              // overlay 32 MiB
    p += nh * 8;
    float* meanb = (float*)p; p += N_TOK * sizeof(float);
    float* rstdb = (float*)p; p += N_TOK * sizeof(float);
    unsigned short* wtqkv = (unsigned short*)p; p += (size_t)3 * QKVM * HID * 2;
    unsigned short* wth   = (unsigned short*)p; p += (size_t)3 * HID * HID * 2;
    unsigned short* wtf1  = (unsigned short*)p; p += (size_t)3 * FFDIM * HID * 2;
    unsigned short* wtf2  = (unsigned short*)p; p += (size_t)3 * HID * FFDIM * 2;
    float* bqkv = (float*)p; p += (size_t)3 * QKVM * sizeof(float);
    float* bf1f = (float*)p; p += (size_t)3 * FFDIM * sizeof(float);
    float* Sqkv = (float*)p; p += (size_t)3 * QKVM * sizeof(float);
    float* Sf1  = (float*)p; p += (size_t)3 * FFDIM * sizeof(float);
    float* pkv  = (float*)p; p += (size_t)256 * HID * sizeof(float);
    float* pks  = (float*)p; p += (size_t)256 * HID * sizeof(float);
    float* psq  = (float*)p; p += 512 * sizeof(float);
    float* psk  = (float*)p; p += 1024 * sizeof(float);
    float* kvs  = (float*)p; p += HID * sizeof(float);
    float* kss  = (float*)p; p += HID * sizeof(float);
    float* scal = (float*)p; p += 256;

    // ---- prep: q cols 0..255; k at 256+2j; v at 257+2j (interleaved) ----
    const size_t qkvLS = (size_t)QKVM * HID;
    wconv<<<dim3(8, 8, 3),  256, 0, stream>>>(Wq,  g1q,  wtqkv, HID, HID, qkvLS, 0,   1);
    wconv<<<dim3(8, 8, 3),  256, 0, stream>>>(Wk,  g1kv, wtqkv, HID, HID, qkvLS, 256, 2);
    wconv<<<dim3(8, 8, 3),  256, 0, stream>>>(Wv,  g1kv, wtqkv, HID, HID, qkvLS, 257, 2);
    wconv<<<dim3(8, 8, 3),  256, 0, stream>>>(Wh,  nullptr, wth, HID, HID, (size_t)HID * HID, 0, 1);
    wconv<<<dim3(8, 32, 3), 256, 0, stream>>>(Wf1, g2,   wtf1, HID, FFDIM, (size_t)FFDIM * HID, 0, 1);
    wconv<<<dim3(32, 8, 3), 256, 0, stream>>>(Wf2, nullptr, wtf2, FFDIM, HID, (size_t)HID * FFDIM, 0, 1);
    colsum<<<dim3(3, 3), 256, 0, stream>>>(wtqkv, Sqkv, QKVM);
    colsum<<<dim3(4, 3), 256, 0, stream>>>(wtf1,  Sf1,  FFDIM);
    biasfold<<<dim3(1, 3), 256, 0, stream>>>(Wq,  bq,  b1q,  bqkv, HID, HID, QKVM, 0,   1);
    biasfold<<<dim3(1, 3), 256, 0, stream>>>(Wk,  bk,  b1kv, bqkv, HID, HID, QKVM, 256, 2);
    biasfold<<<dim3(1, 3), 256, 0, stream>>>(Wv,  bv,  b1kv, bqkv, HID, HID, QKVM, 257, 2);
    biasfold<<<dim3(4, 3), 256, 0, stream>>>(Wf1, bf1, b2,   bf1f, HID, FFDIM, FFDIM, 0, 1);
    cast_stats<<<N_TOK / 4, 256, 0, stream>>>(x, hb, meanb, rstdb);

    const int gQKV = (N_TOK / 256) * (QKVM / 128);   // 1536
    const int gF1  = (N_TOK / 256) * (FFDIM / 128);  // 2048
    const int gRN  = N_TOK / 128;                    // 512 (full-row GEMMs)

    for (int l = 0; l < 3; ++l) {
        // QKV: epilogue-LN + fused attention reduction -> qbuf/vbuf + partials
        gemm_rs<HID, true, false, true, false><<<gQKV, 256, 0, stream>>>(
            hb, HID, wtqkv + l * qkvLS, bqkv + l * QKVM, Sqkv + l * QKVM,
            meanb, rstdb, qbuf, HID, QKVM / 128, vbuf, pkv, pks, psq, psk);
        finalize_kernel<<<33, 256, 0, stream>>>(pkv, pks, psq, psk, kvs, kss, scal);
        // H (full-row, ATTN-fused A): attn(q,v) @ Wh + bh + hb -> hpre + stats
        gemm_rn<HID, true, true, false><<<gRN, 256, 0, stream>>>(
            qbuf, HID, vbuf, wth + (size_t)l * HID * HID, bh + (size_t)l * HID,
            hb, hpre, meanb, rstdb, kvs, kss, scal);
        // FFN1: epilogue-LN + GELU -> act (uses hpre stats)
        gemm_rs<HID, true, true, false, false><<<gF1, 256, 0, stream>>>(
            hpre, HID, wtf1 + (size_t)l * FFDIM * HID, bf1f + (size_t)l * FFDIM,
            Sf1 + (size_t)l * FFDIM, meanb, rstdb, act, FFDIM, FFDIM / 128,
            nullptr, nullptr, nullptr, nullptr, nullptr);
        // FFN2 (full-row): + res(hpre) -> next hb (+stats) or final d_out
        if (l < 2)
            gemm_rn<FFDIM, false, true, false><<<gRN, 256, 0, stream>>>(
                act, FFDIM, nullptr, wtf2 + (size_t)l * HID * FFDIM,
                bf2 + (size_t)l * HID, hpre, hb, meanb, rstdb,
                nullptr, nullptr, nullptr);
        else
            gemm_rn<FFDIM, false, false, true><<<gRN, 256, 0, stream>>>(
                act, FFDIM, nullptr, wtf2 + (size_t)l * HID * FFDIM,
                bf2 + (size_t)l * HID, hpre, out, meanb, rstdb,
                nullptr, nullptr, nullptr);
    }
}

// Round 25
// 740.108 us; speedup vs baseline: 1.3088x; 1.2508x over previous
//
#include <hip/hip_runtime.h>
#include <math.h>

#define N_TOK 65536
#define HID   256
#define FFDIM 1024
#define QKVM  768
#define EPS_LN 1e-5f

typedef __bf16 bf16x8 __attribute__((ext_vector_type(8)));
typedef __bf16 bf16x4 __attribute__((ext_vector_type(4)));
typedef float  f32x4  __attribute__((ext_vector_type(4)));
typedef unsigned short u16x8 __attribute__((ext_vector_type(8)));

// tanh-form GELU: x * sigmoid(1.59577*x*(1+0.044715*x^2)); |err| <= ~2e-3
__device__ __forceinline__ float gelu_f(float x) {
    const float t = 1.59576912f * x * fmaf(0.044715f, x * x, 1.0f);
    return x / (1.0f + __expf(-t));
}
__device__ __forceinline__ float bf2f(unsigned short u) {
    return __uint_as_float(((unsigned int)u) << 16);
}
__device__ __forceinline__ unsigned short f2bf(float f) {
    unsigned int x = __float_as_uint(f);
    unsigned int r = ((x >> 16) & 1u) + 0x7fffu;
    return (unsigned short)((x + r) >> 16);
}

// -- weight fp32 [L,K,M] -> bf16 transposed [L][moff + m*mstride][K], g-scaled
__global__ __launch_bounds__(256) void wconv(
    const float* __restrict__ src, const float* __restrict__ g,
    unsigned short* __restrict__ dst,
    const int K, const int M, const size_t dstLS, const int moff, const int mstride)
{
    const int l = blockIdx.z;
    __shared__ float t[32][33];
    const int r  = threadIdx.x >> 3;
    const int c0 = (threadIdx.x & 7) * 4;
    const int bk = blockIdx.x * 32;
    const int bm = blockIdx.y * 32;
    float4 v4 = *(const float4*)(src + (size_t)l * K * M + (size_t)(bk + r) * M + bm + c0);
    if (g) {
        const float gv = g[(size_t)l * K + bk + r];
        v4.x *= gv; v4.y *= gv; v4.z *= gv; v4.w *= gv;
    }
    t[r][c0] = v4.x; t[r][c0+1] = v4.y; t[r][c0+2] = v4.z; t[r][c0+3] = v4.w;
    __syncthreads();
    ushort4 o;
    o.x = f2bf(t[c0+0][r]);
    o.y = f2bf(t[c0+1][r]);
    o.z = f2bf(t[c0+2][r]);
    o.w = f2bf(t[c0+3][r]);
    *(ushort4*)(dst + (size_t)l * dstLS +
                (size_t)(moff + (bm + r) * mstride) * K + bk + c0) = o;
}

// -- parallel biasfold: outb[l][moff+m*mstride] = bias[l][m] + sum_k bv[l][k]*W[l][k][m]
// 256 threads = 32 m-cols x 8 k-slices (chain 256 -> K/8); LDS reduce.
__global__ __launch_bounds__(256) void biasfold(
    const float* __restrict__ W, const float* __restrict__ bias,
    const float* __restrict__ bvec, float* __restrict__ outb,
    const int K, const int M, const size_t outLS, const int moff, const int mstride)
{
    const int l  = blockIdx.y;
    const int mc = threadIdx.x & 31;
    const int m  = blockIdx.x * 32 + mc;
    const int ks = threadIdx.x >> 5;           // 0..7
    const int kchunk = K >> 3;
    const float* Wl = W + (size_t)l * K * M;
    const float* bv = bvec + (size_t)l * K;
    float acc = 0.f;
    for (int i = 0; i < kchunk; ++i) {
        const int k = ks * kchunk + i;
        acc = fmaf(bv[k], Wl[(size_t)k * M + m], acc);
    }
    __shared__ float red[8][32];
    red[ks][mc] = acc;
    __syncthreads();
    if (ks == 0) {
        float t = bias[(size_t)l * M + m];
        #pragma unroll
        for (int j = 0; j < 8; ++j) t += red[j][mc];
        outb[(size_t)l * outLS + moff + (size_t)m * mstride] = t;
    }
}

__global__ __launch_bounds__(256) void colsum(
    const unsigned short* __restrict__ wt, float* __restrict__ S, const int M)
{
    const int l = blockIdx.y;
    const int j = blockIdx.x * 256 + threadIdx.x;
    const unsigned short* rowp = wt + (size_t)l * M * HID + (size_t)j * HID;
    float s = 0.f;
    for (int k = 0; k < HID; k += 8) {
        const u16x8 u = *(const u16x8*)(rowp + k);
        #pragma unroll
        for (int t = 0; t < 8; ++t) s += bf2f(u[t]);
    }
    S[(size_t)l * M + j] = s;
}

// ------- fp32 -> bf16 cast + fused row stats ---------------------------------
__global__ __launch_bounds__(256) void cast_stats(
    const float* __restrict__ x, unsigned short* __restrict__ hb,
    float* __restrict__ mean, float* __restrict__ rstd)
{
    const int row  = blockIdx.x * 4 + (threadIdx.x >> 6);
    const int lane = threadIdx.x & 63;
    const size_t base = (size_t)row * HID + lane * 4;
    const float4 xv = *(const float4*)(x + base);
    ushort4 o;
    o.x = f2bf(xv.x); o.y = f2bf(xv.y); o.z = f2bf(xv.z); o.w = f2bf(xv.w);
    *(ushort4*)(hb + base) = o;
    float s  = xv.x + xv.y + xv.z + xv.w;
    float s2 = fmaf(xv.x, xv.x, fmaf(xv.y, xv.y, fmaf(xv.z, xv.z, xv.w * xv.w)));
    #pragma unroll
    for (int off = 32; off > 0; off >>= 1) {
        s  += __shfl_xor(s, off, 64);
        s2 += __shfl_xor(s2, off, 64);
    }
    if (lane == 0) {
        const float m   = s * (1.0f / HID);
        const float var = fmaxf(s2 * (1.0f / HID) - m * m, 0.f);
        mean[row] = m;
        rstd[row] = rsqrtf(var + EPS_LN);
    }
}

// ------- 256x128-tile GEMM + 2-deep reg prefetch: LN-ep, GELU, fused reduce ---
template<int K, bool LNEP, bool GELU_EP, bool REDUCE, bool OUTF32>
__global__ __launch_bounds__(256, 2) void gemm_rs(
    const unsigned short* __restrict__ A, const int lda,
    const unsigned short* __restrict__ Wt,
    const float* __restrict__ Bias, const float* __restrict__ S,
    const float* __restrict__ mean, const float* __restrict__ rstd,
    void* __restrict__ C, const int ldc, const int nCT,
    unsigned short* __restrict__ Cv,
    float* __restrict__ pkv, float* __restrict__ pks,
    float* __restrict__ psq, float* __restrict__ psk)
{
    constexpr int KT  = K / 32;          // 8 (even)
    constexpr int LDT = 40;
    __shared__ __align__(16) unsigned short Abuf[2][256 * LDT];   // 40 KB
    __shared__ __align__(16) unsigned short Bbuf[2][128 * LDT];   // 20 KB
    __shared__ float redKV[2][64];
    __shared__ float redKS[2][64];
    __shared__ float sredS[4];
    const int tid = threadIdx.x;
    const int gsz = nCT << 3;
    const int grp = blockIdx.x / gsz;
    const int rem = blockIdx.x - grp * gsz;
    const int bm  = ((grp << 3) + (rem & 7)) << 8;   // 256-row tile (fastest)
    const int bn  = (rem >> 3) << 7;                 // 128-col tile
    const int lr = tid >> 2;
    const int lk = (tid & 3) << 3;
    const unsigned short* Ag = A  + (size_t)(bm + lr) * lda + lk;
    const unsigned short* Bg = Wt + (size_t)(bn + lr) * K   + lk;
    const int lds_off = lr * LDT + lk;

    const int lane = tid & 63;
    const int wv   = tid >> 6;
    const int wr   = (wv >> 1) << 7;   // 0 / 128
    const int wc   = (wv & 1) << 6;    // 0 / 64
    const int lrow = lane & 15;
    const int kgrp = lane >> 4;

    f32x4 acc[8][4];
    #pragma unroll
    for (int i = 0; i < 8; ++i)
        #pragma unroll
        for (int j = 0; j < 4; ++j)
            acc[i][j] = (f32x4){0.f, 0.f, 0.f, 0.f};

    // two named register sets (2-deep prefetch; static indexing per rule #20)
    u16x8 aA0, aA1, aA2, aA3, bA0, bA1;
    u16x8 aB0, aB1, aB2, aB3, bB0, bB1;
    #define GLOADA_RS(kt) { const unsigned short* a_ = Ag + (kt) * 32;           \
        const unsigned short* b_ = Bg + (kt) * 32;                               \
        aA0 = *(const u16x8*)a_;                                                 \
        aA1 = *(const u16x8*)(a_ + (size_t)64  * lda);                           \
        aA2 = *(const u16x8*)(a_ + (size_t)128 * lda);                           \
        aA3 = *(const u16x8*)(a_ + (size_t)192 * lda);                           \
        bA0 = *(const u16x8*)b_;                                                 \
        bA1 = *(const u16x8*)(b_ + (size_t)64 * K); }
    #define GLOADB_RS(kt) { const unsigned short* a_ = Ag + (kt) * 32;           \
        const unsigned short* b_ = Bg + (kt) * 32;                               \
        aB0 = *(const u16x8*)a_;                                                 \
        aB1 = *(const u16x8*)(a_ + (size_t)64  * lda);                           \
        aB2 = *(const u16x8*)(a_ + (size_t)128 * lda);                           \
        aB3 = *(const u16x8*)(a_ + (size_t)192 * lda);                           \
        bB0 = *(const u16x8*)b_;                                                 \
        bB1 = *(const u16x8*)(b_ + (size_t)64 * K); }
    #define LSTOREA_RS(buf) {                                                    \
        *(u16x8*)&Abuf[buf][lds_off]             = aA0;                          \
        *(u16x8*)&Abuf[buf][lds_off + 64  * LDT] = aA1;                          \
        *(u16x8*)&Abuf[buf][lds_off + 128 * LDT] = aA2;                          \
        *(u16x8*)&Abuf[buf][lds_off + 192 * LDT] = aA3;                          \
        *(u16x8*)&Bbuf[buf][lds_off]             = bA0;                          \
        *(u16x8*)&Bbuf[buf][lds_off + 64  * LDT] = bA1; }
    #define LSTOREB_RS(buf) {                                                    \
        *(u16x8*)&Abuf[buf][lds_off]             = aB0;                          \
        *(u16x8*)&Abuf[buf][lds_off + 64  * LDT] = aB1;                          \
        *(u16x8*)&Abuf[buf][lds_off + 128 * LDT] = aB2;                          \
        *(u16x8*)&Abuf[buf][lds_off + 192 * LDT] = aB3;                          \
        *(u16x8*)&Bbuf[buf][lds_off]             = bB0;                          \
        *(u16x8*)&Bbuf[buf][lds_off + 64  * LDT] = bB1; }
    #define MFMAS_RS(buf) {                                                      \
        bf16x8 af[8], bfr[4];                                                    \
        _Pragma("unroll")                                                        \
        for (int ni = 0; ni < 4; ++ni)                                           \
            bfr[ni] = *(const bf16x8*)&Bbuf[buf][(wc + ni * 16 + lrow) * LDT + kgrp * 8]; \
        _Pragma("unroll")                                                        \
        for (int mi = 0; mi < 8; ++mi)                                           \
            af[mi] = *(const bf16x8*)&Abuf[buf][(wr + mi * 16 + lrow) * LDT + kgrp * 8]; \
        _Pragma("unroll")                                                        \
        for (int mi = 0; mi < 8; ++mi)                                           \
            _Pragma("unroll")                                                    \
            for (int ni = 0; ni < 4; ++ni)                                       \
                acc[mi][ni] = __builtin_amdgcn_mfma_f32_16x16x32_bf16(           \
                    bfr[ni], af[mi], acc[mi][ni], 0, 0, 0); }

    GLOADA_RS(0);
    GLOADB_RS(1);
    LSTOREA_RS(0);
    __syncthreads();
    #pragma unroll
    for (int kt2 = 0; kt2 < KT; kt2 += 2) {
        LSTOREB_RS(1);                         // loads >=2 phases old
        if (kt2 + 2 < KT) GLOADA_RS(kt2 + 2);
        MFMAS_RS(0);
        __syncthreads();
        if (kt2 + 2 < KT) {
            LSTOREA_RS(0);
            if (kt2 + 3 < KT) GLOADB_RS(kt2 + 3);
        }
        MFMAS_RS(1);
        if (kt2 + 2 < KT) __syncthreads();
    }
    #undef GLOADA_RS
    #undef GLOADB_RS
    #undef LSTOREA_RS
    #undef LSTOREB_RS
    #undef MFMAS_RS

    float4 bcol[4], scol[4];
    #pragma unroll
    for (int ni = 0; ni < 4; ++ni) {
        const int col0 = bn + wc + ni * 16 + (kgrp << 2);
        bcol[ni] = *(const float4*)(Bias + col0);
        if (LNEP) scol[ni] = *(const float4*)(S + col0);
    }
    const bool isQ = (bn < 256);
    float acKV[4][2] = {}, acKS[4][2] = {};
    float scal1 = 0.f;
    #pragma unroll
    for (int mi = 0; mi < 8; ++mi) {
        const int row = bm + wr + mi * 16 + lrow;
        float mrow = 0.f, rsrow = 0.f;
        if (LNEP) { mrow = mean[row]; rsrow = rstd[row]; }
        const size_t rowC = (size_t)row * ldc;
        #pragma unroll
        for (int ni = 0; ni < 4; ++ni) {
            const int col0 = bn + wc + ni * 16 + (kgrp << 2);
            float v[4];
            #pragma unroll
            for (int r = 0; r < 4; ++r) v[r] = acc[mi][ni][r];
            if (LNEP) {
                v[0] = fmaf(v[0] - mrow * scol[ni].x, rsrow, bcol[ni].x);
                v[1] = fmaf(v[1] - mrow * scol[ni].y, rsrow, bcol[ni].y);
                v[2] = fmaf(v[2] - mrow * scol[ni].z, rsrow, bcol[ni].z);
                v[3] = fmaf(v[3] - mrow * scol[ni].w, rsrow, bcol[ni].w);
            } else {
                v[0] += bcol[ni].x; v[1] += bcol[ni].y;
                v[2] += bcol[ni].z; v[3] += bcol[ni].w;
            }
            if (GELU_EP) {
                v[0] = gelu_f(v[0]); v[1] = gelu_f(v[1]);
                v[2] = gelu_f(v[2]); v[3] = gelu_f(v[3]);
            }
            if (REDUCE && !isQ) {
                acKV[ni][0] = fmaf(v[0], v[1], acKV[ni][0]);
                acKV[ni][1] = fmaf(v[2], v[3], acKV[ni][1]);
                acKS[ni][0] += v[0];
                acKS[ni][1] += v[2];
                scal1 = fmaf(v[0], v[0], fmaf(v[2], v[2], scal1));
                const unsigned int pk2 =
                    (unsigned int)f2bf(v[1]) | ((unsigned int)f2bf(v[3]) << 16);
                *(unsigned int*)(Cv + (size_t)row * HID + ((col0 - 256) >> 1)) = pk2;
            } else {
                if (REDUCE) {
                    scal1 = fmaf(v[0], v[0], fmaf(v[1], v[1],
                             fmaf(v[2], v[2], fmaf(v[3], v[3], scal1))));
                }
                if (OUTF32) {
                    float4 o = {v[0], v[1], v[2], v[3]};
                    *(float4*)((float*)C + rowC + col0) = o;
                } else {
                    bf16x4 o = {(__bf16)v[0], (__bf16)v[1], (__bf16)v[2], (__bf16)v[3]};
                    *(bf16x4*)((unsigned short*)C + rowC + col0) = o;
                }
            }
        }
    }
    if (REDUCE) {
        const int rowG = bm >> 8;
        #pragma unroll
        for (int off = 32; off > 0; off >>= 1) scal1 += __shfl_xor(scal1, off, 64);
        if (lane == 0) sredS[wv] = scal1;
        if (!isQ) {
            #pragma unroll
            for (int ni = 0; ni < 4; ++ni)
                #pragma unroll
                for (int pr = 0; pr < 2; ++pr) {
                    float a = acKV[ni][pr], b = acKS[ni][pr];
                    #pragma unroll
                    for (int off = 1; off < 16; off <<= 1) {
                        a += __shfl_xor(a, off, 64);
                        b += __shfl_xor(b, off, 64);
                    }
                    if (lrow == 0) {
                        const int p = (wc >> 1) + ni * 8 + (kgrp << 1) + pr;
                        redKV[wv >> 1][p] = a;
                        redKS[wv >> 1][p] = b;
                    }
                }
        }
        __syncthreads();
        if (tid == 0) {
            const float t = sredS[0] + sredS[1] + sredS[2] + sredS[3];
            if (isQ) psq[rowG * 2 + (bn >> 7)] = t;
            else     psk[rowG * 4 + ((bn - 256) >> 7)] = t;
        }
        if (!isQ && tid < 64) {
            const int cb = (bn - 256) >> 1;
            pkv[(size_t)rowG * 256 + cb + tid] = redKV[0][tid] + redKV[1][tid];
            pks[(size_t)rowG * 256 + cb + tid] = redKS[0][tid] + redKS[1][tid];
        }
    }
}

// ------- full-row GEMM (M=256): R20 1-deep core; ATTN staging; fused stats ----
template<int K, bool ATTN, bool STATS, bool OUTF32>
__global__ __launch_bounds__(256, 2) void gemm_rn(
    const unsigned short* __restrict__ A, const int lda,
    const unsigned short* __restrict__ Av,
    const unsigned short* __restrict__ Wt,            // [256][K]
    const float* __restrict__ Bias,
    const unsigned short* __restrict__ res,           // [.][256] bf16
    void* __restrict__ C,                             // [.][256]
    float* __restrict__ meanO, float* __restrict__ rstdO,
    const float* __restrict__ kvs, const float* __restrict__ kss,
    const float* __restrict__ scal)
{
    constexpr int KT  = K / 32;
    constexpr int LDT = 40;
    __shared__ __align__(16) unsigned short Abuf[2][128 * LDT];   // 20 KB
    __shared__ __align__(16) unsigned short Bbuf[2][256 * LDT];   // 40 KB
    __shared__ float sredS[128][2];
    __shared__ float sredQ[128][2];
    const int tid = threadIdx.x;
    const int bm  = blockIdx.x << 7;                 // 128-row tile
    const int lr = tid >> 2;
    const int lk = (tid & 3) << 3;
    const unsigned short* Ag = A  + (size_t)(bm + lr) * lda + lk;
    const unsigned short* Bg = Wt + (size_t)lr * K + lk;
    const int lds_off = lr * LDT + lk;

    const int lane = tid & 63;
    const int wv   = tid >> 6;
    const int wr   = (wv >> 1) << 6;   // 0 / 64
    const int wc   = (wv & 1) << 7;    // 0 / 128
    const int lrow = lane & 15;
    const int kgrp = lane >> 4;

    const float inv = ATTN ? scal[0] : 0.f;

    f32x4 acc[4][8];
    #pragma unroll
    for (int i = 0; i < 4; ++i)
        #pragma unroll
        for (int j = 0; j < 8; ++j)
            acc[i][j] = (f32x4){0.f, 0.f, 0.f, 0.f};

    u16x8 ra0, ra1, rb0, rb1, rb2, rb3;
    auto gload = [&](int kt) {
        const unsigned short* b = Bg + kt * 32;
        rb0 = *(const u16x8*)b;
        rb1 = *(const u16x8*)(b + (size_t)64  * K);
        rb2 = *(const u16x8*)(b + (size_t)128 * K);
        rb3 = *(const u16x8*)(b + (size_t)192 * K);
        if constexpr (ATTN) {
            const int col = kt * 32 + lk;              // head kt, cols col..col+7
            float kvsL[8], kssL[8];
            *(float4*)&kvsL[0] = *(const float4*)(kvs + col);
            *(float4*)&kvsL[4] = *(const float4*)(kvs + col + 4);
            *(float4*)&kssL[0] = *(const float4*)(kss + col);
            *(float4*)&kssL[4] = *(const float4*)(kss + col + 4);
            #pragma unroll
            for (int half = 0; half < 2; ++half) {
                const size_t rbase = (size_t)(bm + lr + half * 64) * 256;
                const u16x8 q8 = *(const u16x8*)(A  + rbase + col);
                const u16x8 v8 = *(const u16x8*)(Av + rbase + col);
                float qf[8];
                float dot = 0.f;
                #pragma unroll
                for (int j = 0; j < 8; ++j) {
                    qf[j] = bf2f(q8[j]);
                    dot = fmaf(qf[j], kssL[j], dot);
                }
                dot += __shfl_xor(dot, 1, 4);          // quad = one head's 32 cols
                dot += __shfl_xor(dot, 2, 4);
                const float rden = 1.0f / fmaf(dot, inv, (float)N_TOK);
                u16x8 o;
                #pragma unroll
                for (int j = 0; j < 8; ++j)
                    o[j] = f2bf(fmaf(qf[j] * kvsL[j], inv,
                                     bf2f(v8[j]) * (float)N_TOK) * rden);
                if (half == 0) ra0 = o; else ra1 = o;
            }
        } else {
            const unsigned short* a = Ag + kt * 32;
            ra0 = *(const u16x8*)a;
            ra1 = *(const u16x8*)(a + (size_t)64 * lda);
        }
    };
    auto lstore = [&](int buf) {
        *(u16x8*)&Abuf[buf][lds_off]             = ra0;
        *(u16x8*)&Abuf[buf][lds_off + 64 * LDT]  = ra1;
        *(u16x8*)&Bbuf[buf][lds_off]             = rb0;
        *(u16x8*)&Bbuf[buf][lds_off + 64  * LDT] = rb1;
        *(u16x8*)&Bbuf[buf][lds_off + 128 * LDT] = rb2;
        *(u16x8*)&Bbuf[buf][lds_off + 192 * LDT] = rb3;
    };

    gload(0);
    lstore(0);
    __syncthreads();
    for (int kt = 0; kt < KT; ++kt) {
        const int cur = kt & 1;
        if (kt + 1 < KT) gload(kt + 1);
        bf16x8 af[4], bfr[8];
        #pragma unroll
        for (int ni = 0; ni < 8; ++ni)
            bfr[ni] = *(const bf16x8*)&Bbuf[cur][(wc + ni * 16 + lrow) * LDT + kgrp * 8];
        #pragma unroll
        for (int mi = 0; mi < 4; ++mi)
            af[mi] = *(const bf16x8*)&Abuf[cur][(wr + mi * 16 + lrow) * LDT + kgrp * 8];
        #pragma unroll
        for (int mi = 0; mi < 4; ++mi)
            #pragma unroll
            for (int ni = 0; ni < 8; ++ni)
                acc[mi][ni] = __builtin_amdgcn_mfma_f32_16x16x32_bf16(
                    bfr[ni], af[mi], acc[mi][ni], 0, 0, 0);   // C^T frags
        if (kt + 1 < KT) {
            lstore(cur ^ 1);
            __syncthreads();
        }
    }
    float sS[4], sQ[4];
    #pragma unroll
    for (int mi = 0; mi < 4; ++mi) { sS[mi] = 0.f; sQ[mi] = 0.f; }
    #pragma unroll
    for (int mi = 0; mi < 4; ++mi) {
        const int row = bm + wr + mi * 16 + lrow;
        const size_t rowC = (size_t)row * HID;
        #pragma unroll
        for (int ni = 0; ni < 8; ++ni) {
            const int col0 = wc + ni * 16 + (kgrp << 2);
            const float4 bcol = *(const float4*)(Bias + col0);
            const ushort4 rv = *(const ushort4*)(res + rowC + col0);
            float v[4];
            #pragma unroll
            for (int r = 0; r < 4; ++r) v[r] = acc[mi][ni][r];
            v[0] += bcol.x + bf2f(rv.x);
            v[1] += bcol.y + bf2f(rv.y);
            v[2] += bcol.z + bf2f(rv.z);
            v[3] += bcol.w + bf2f(rv.w);
            if (STATS) {
                sS[mi] += v[0] + v[1] + v[2] + v[3];
                sQ[mi] = fmaf(v[0], v[0], fmaf(v[1], v[1],
                          fmaf(v[2], v[2], fmaf(v[3], v[3], sQ[mi]))));
            }
            if (OUTF32) {
                float4 o = {v[0], v[1], v[2], v[3]};
                *(float4*)((float*)C + rowC + col0) = o;
            } else {
                bf16x4 o = {(__bf16)v[0], (__bf16)v[1], (__bf16)v[2], (__bf16)v[3]};
                *(bf16x4*)((unsigned short*)C + rowC + col0) = o;
            }
        }
    }
    if (STATS) {
        #pragma unroll
        for (int mi = 0; mi < 4; ++mi) {
            sS[mi] += __shfl_xor(sS[mi], 16, 64);
            sS[mi] += __shfl_xor(sS[mi], 32, 64);
            sQ[mi] += __shfl_xor(sQ[mi], 16, 64);
            sQ[mi] += __shfl_xor(sQ[mi], 32, 64);
        }
        __syncthreads();
        if (lane < 16) {
            #pragma unroll
            for (int mi = 0; mi < 4; ++mi) {
                const int ridx = wr + mi * 16 + lrow;
                sredS[ridx][wv & 1] = sS[mi];
                sredQ[ridx][wv & 1] = sQ[mi];
            }
        }
        __syncthreads();
        if ((wv & 1) == 0 && lane < 16) {
            #pragma unroll
            for (int mi = 0; mi < 4; ++mi) {
                const int ridx = wr + mi * 16 + lrow;
                const float Ssum = sredS[ridx][0] + sredS[ridx][1];
                const float Qsum = sredQ[ridx][0] + sredQ[ridx][1];
                const float m    = Ssum * (1.0f / HID);
                const float var  = fmaxf(Qsum * (1.0f / HID) - m * m, 0.f);
                meanO[bm + ridx] = m;
                rstdO[bm + ridx] = rsqrtf(var + EPS_LN);
            }
        }
    }
}

// ------- parallel finalize: 32 blocks of column sums + 1 block of scalars -----
__global__ __launch_bounds__(256) void finalize_kernel(
    const float* __restrict__ pkv, const float* __restrict__ pks,
    const float* __restrict__ psq, const float* __restrict__ psk,
    float* __restrict__ kvsum, float* __restrict__ kssum, float* __restrict__ scal)
{
    const int blk = blockIdx.x;
    const int tid = threadIdx.x;
    if (blk < 32) {
        const int col = blk * 8 + (tid >> 5);
        const int sub = tid & 31;
        float kv = 0.f, ks = 0.f;
        #pragma unroll
        for (int j = 0; j < 8; ++j) {
            const int rg = sub + (j << 5);
            kv += pkv[(size_t)rg * HID + col];
            ks += pks[(size_t)rg * HID + col];
        }
        #pragma unroll
        for (int off = 16; off > 0; off >>= 1) {
            kv += __shfl_xor(kv, off, 32);
            ks += __shfl_xor(ks, off, 32);
        }
        if (sub == 0) { kvsum[col] = kv; kssum[col] = ks; }
    } else {
        float sq = psq[tid] + psq[tid + 256];
        float sk = psk[tid] + psk[tid + 256] + psk[tid + 512] + psk[tid + 768];
        #pragma unroll
        for (int off = 32; off > 0; off >>= 1) {
            sq += __shfl_xor(sq, off, 64);
            sk += __shfl_xor(sk, off, 64);
        }
        __shared__ float s1[4], s2[4];
        if ((tid & 63) == 0) { s1[tid >> 6] = sq; s2[tid >> 6] = sk; }
        __syncthreads();
        if (tid == 0) {
            const float SQ = s1[0] + s1[1] + s1[2] + s1[3];
            const float SK = s2[0] + s2[1] + s2[2] + s2[3];
            scal[0] = rsqrtf(SQ * SK);
        }
    }
}

extern "C" void kernel_launch(void* const* d_in, const int* in_sizes, int n_in,
                              void* d_out, int out_size, void* d_ws, size_t ws_size,
                              hipStream_t stream) {
    const float* x    = (const float*)d_in[0];
    const float* Wq   = (const float*)d_in[1];
    const float* bq   = (const float*)d_in[2];
    const float* Wk   = (const float*)d_in[3];
    const float* bk   = (const float*)d_in[4];
    const float* Wv   = (const float*)d_in[5];
    const float* bv   = (const float*)d_in[6];
    const float* Wh   = (const float*)d_in[7];
    const float* bh   = (const float*)d_in[8];
    const float* g1kv = (const float*)d_in[9];
    const float* b1kv = (const float*)d_in[10];
    const float* g1q  = (const float*)d_in[11];
    const float* b1q  = (const float*)d_in[12];
    const float* Wf1  = (const float*)d_in[13];
    const float* bf1  = (const float*)d_in[14];
    const float* Wf2  = (const float*)d_in[15];
    const float* bf2  = (const float*)d_in[16];
    const float* g2   = (const float*)d_in[17];
    const float* b2   = (const float*)d_in[18];
    float* out = (float*)d_out;

    // ---- workspace (~200 MiB; limit ~256 MiB) ----
    char* p = (char*)d_ws;
    const size_t nh = (size_t)N_TOK * HID;
    unsigned short* hb   = (unsigned short*)p; p += nh * 2;       // 32 MiB
    unsigned short* hpre = (unsigned short*)p; p += nh * 2;       // 32 MiB
    unsigned short* act  = (unsigned short*)p;                    // 128 MiB
    unsigned short* qbuf = act;                                   // overlay 32 MiB
    unsigned short* vbuf = act + nh;                              // overlay 32 MiB
    p += nh * 8;
    float* meanb = (float*)p; p += N_TOK * sizeof(float);
    float* rstdb = (float*)p; p += N_TOK * sizeof(float);
    unsigned short* wtqkv = (unsigned short*)p; p += (size_t)3 * QKVM * HID * 2;
    unsigned short* wth   = (unsigned short*)p; p += (size_t)3 * HID * HID * 2;
    unsigned short* wtf1  = (unsigned short*)p; p += (size_t)3 * FFDIM * HID * 2;
    unsigned short* wtf2  = (unsigned short*)p; p += (size_t)3 * HID * FFDIM * 2;
    float* bqkv = (float*)p; p += (size_t)3 * QKVM * sizeof(float);
    float* bf1f = (float*)p; p += (size_t)3 * FFDIM * sizeof(float);
    float* Sqkv = (float*)p; p += (size_t)3 * QKVM * sizeof(float);
    float* Sf1  = (float*)p; p += (size_t)3 * FFDIM * sizeof(float);
    float* pkv  = (float*)p; p += (size_t)256 * HID * sizeof(float);
    float* pks  = (float*)p; p += (size_t)256 * HID * sizeof(float);
    float* psq  = (float*)p; p += 512 * sizeof(float);
    float* psk  = (float*)p; p += 1024 * sizeof(float);
    float* kvs  = (float*)p; p += HID * sizeof(float);
    float* kss  = (float*)p; p += HID * sizeof(float);
    float* scal = (float*)p; p += 256;

    // ---- prep: q cols 0..255; k at 256+2j; v at 257+2j (interleaved) ----
    const size_t qkvLS = (size_t)QKVM * HID;
    wconv<<<dim3(8, 8, 3),  256, 0, stream>>>(Wq,  g1q,  wtqkv, HID, HID, qkvLS, 0,   1);
    wconv<<<dim3(8, 8, 3),  256, 0, stream>>>(Wk,  g1kv, wtqkv, HID, HID, qkvLS, 256, 2);
    wconv<<<dim3(8, 8, 3),  256, 0, stream>>>(Wv,  g1kv, wtqkv, HID, HID, qkvLS, 257, 2);
    wconv<<<dim3(8, 8, 3),  256, 0, stream>>>(Wh,  nullptr, wth, HID, HID, (size_t)HID * HID, 0, 1);
    wconv<<<dim3(8, 32, 3), 256, 0, stream>>>(Wf1, g2,   wtf1, HID, FFDIM, (size_t)FFDIM * HID, 0, 1);
    wconv<<<dim3(32, 8, 3), 256, 0, stream>>>(Wf2, nullptr, wtf2, FFDIM, HID, (size_t)HID * FFDIM, 0, 1);
    colsum<<<dim3(3, 3), 256, 0, stream>>>(wtqkv, Sqkv, QKVM);
    colsum<<<dim3(4, 3), 256, 0, stream>>>(wtf1,  Sf1,  FFDIM);
    biasfold<<<dim3(8, 3),  256, 0, stream>>>(Wq,  bq,  b1q,  bqkv, HID, HID, QKVM, 0,   1);
    biasfold<<<dim3(8, 3),  256, 0, stream>>>(Wk,  bk,  b1kv, bqkv, HID, HID, QKVM, 256, 2);
    biasfold<<<dim3(8, 3),  256, 0, stream>>>(Wv,  bv,  b1kv, bqkv, HID, HID, QKVM, 257, 2);
    biasfold<<<dim3(32, 3), 256, 0, stream>>>(Wf1, bf1, b2,   bf1f, HID, FFDIM, FFDIM, 0, 1);
    cast_stats<<<N_TOK / 4, 256, 0, stream>>>(x, hb, meanb, rstdb);

    const int gQKV = (N_TOK / 256) * (QKVM / 128);   // 1536
    const int gF1  = (N_TOK / 256) * (FFDIM / 128);  // 2048
    const int gRN  = N_TOK / 128;                    // 512 (full-row GEMMs)

    for (int l = 0; l < 3; ++l) {
        // QKV: epilogue-LN + fused attention reduction -> qbuf/vbuf + partials
        gemm_rs<HID, true, false, true, false><<<gQKV, 256, 0, stream>>>(
            hb, HID, wtqkv + l * qkvLS, bqkv + l * QKVM, Sqkv + l * QKVM,
            meanb, rstdb, qbuf, HID, QKVM / 128, vbuf, pkv, pks, psq, psk);
        finalize_kernel<<<33, 256, 0, stream>>>(pkv, pks, psq, psk, kvs, kss, scal);
        // H (full-row, ATTN-fused A): attn(q,v) @ Wh + bh + hb -> hpre + stats
        gemm_rn<HID, true, true, false><<<gRN, 256, 0, stream>>>(
            qbuf, HID, vbuf, wth + (size_t)l * HID * HID, bh + (size_t)l * HID,
            hb, hpre, meanb, rstdb, kvs, kss, scal);
        // FFN1: epilogue-LN + GELU -> act (uses hpre stats)
        gemm_rs<HID, true, true, false, false><<<gF1, 256, 0, stream>>>(
            hpre, HID, wtf1 + (size_t)l * FFDIM * HID, bf1f + (size_t)l * FFDIM,
            Sf1 + (size_t)l * FFDIM, meanb, rstdb, act, FFDIM, FFDIM / 128,
            nullptr, nullptr, nullptr, nullptr, nullptr);
        // FFN2 (full-row): + res(hpre) -> next hb (+stats) or final d_out
        if (l < 2)
            gemm_rn<FFDIM, false, true, false><<<gRN, 256, 0, stream>>>(
                act, FFDIM, nullptr, wtf2 + (size_t)l * HID * FFDIM,
                bf2 + (size_t)l * HID, hpre, hb, meanb, rstdb,
                nullptr, nullptr, nullptr);
        else
            gemm_rn<FFDIM, false, false, true><<<gRN, 256, 0, stream>>>(
                act, FFDIM, nullptr, wtf2 + (size_t)l * HID * FFDIM,
                bf2 + (size_t)l * HID, hpre, out, meanb, rstdb,
                nullptr, nullptr, nullptr);
    }
}